// Round 1
// baseline (2179.681 us; speedup 1.0000x reference)
//
#include <hip/hip_runtime.h>
#include <hip/hip_bf16.h>

#define CN0 200000
#define CN1 100000
#define CN2 50000
#define CE0 1600000
#define CE1 800000
#define CEP 500000
#define CIN 64
#define CH  128
#define CEIN 16
#define CMH 128
#define CNCLS 8

// ---------------- scatter: agg[dst] += x[src], deg[dst] += 1 ----------------
template<int LOGF>
__global__ void k_scatter(const float* __restrict__ x, const int* __restrict__ src,
                          const int* __restrict__ dst, float* __restrict__ agg,
                          float* __restrict__ deg, int nedges) {
  int t = blockIdx.x * blockDim.x + threadIdx.x;
  int e = t >> LOGF;
  if (e >= nedges) return;
  int lane = t & ((1 << LOGF) - 1);
  int s = src[e], d = dst[e];
  atomicAdd(&agg[((long long)d << LOGF) + lane], x[((long long)s << LOGF) + lane]);
  if (lane == 0) atomicAdd(&deg[d], 1.0f);
}

// ---------------- SAGE layer: out = x@Ws + (agg/deg)@Wn + b ----------------
// block = 128 threads (one per output col), ROWS rows per block.
// x/agg reads are wave-uniform -> scalar loads; weight reads coalesced.
template<int K, int ROWS>
__global__ __launch_bounds__(128) void k_sage(
    const float* __restrict__ x, const float* __restrict__ agg,
    const float* __restrict__ deg,
    const float* __restrict__ Ws, const float* __restrict__ Wn,
    const float* __restrict__ b, float* __restrict__ out) {
  int c = threadIdx.x;              // 0..127
  int r0 = blockIdx.x * ROWS;
  float acc[ROWS], invd[ROWS];
  float bias = b[c];
#pragma unroll
  for (int i = 0; i < ROWS; i++) {
    acc[i] = bias;
    invd[i] = 1.0f / fmaxf(deg[r0 + i], 1.0f);
  }
  for (int k = 0; k < K; k++) {
    float ws = Ws[k * CH + c];
    float wn = Wn[k * CH + c];
#pragma unroll
    for (int i = 0; i < ROWS; i++) {
      acc[i] = fmaf(x[(long long)(r0 + i) * K + k], ws, acc[i]);
      acc[i] = fmaf(agg[(long long)(r0 + i) * K + k] * invd[i], wn, acc[i]);
    }
  }
#pragma unroll
  for (int i = 0; i < ROWS; i++) out[(long long)(r0 + i) * CH + c] = acc[i];
}

// ---------------- column stats: stats[c]=sum, stats[128+c]=sumsq ----------------
__global__ void k_colstats(const float* __restrict__ h, int nrows,
                           float* __restrict__ stats) {
  int c = threadIdx.x & 127;
  int sub = threadIdx.x >> 7;          // 0..1
  int rpb = blockDim.x >> 7;           // 2
  int r = blockIdx.x * rpb + sub;
  int rstep = gridDim.x * rpb;
  float s = 0.f, ss = 0.f;
  for (; r < nrows; r += rstep) {
    float v = h[(long long)r * CH + c];
    s += v;
    ss = fmaf(v, v, ss);
  }
  atomicAdd(&stats[c], s);
  atomicAdd(&stats[CH + c], ss);
}

// ---------------- BN (biased var) + ReLU, in place ----------------
__global__ void k_bnrelu(float* __restrict__ h, int nrows,
                         const float* __restrict__ stats,
                         const float* __restrict__ g, const float* __restrict__ be) {
  int total = nrows * CH;
  float inv_n = 1.0f / (float)nrows;
  for (int t = blockIdx.x * blockDim.x + threadIdx.x; t < total;
       t += gridDim.x * blockDim.x) {
    int c = t & 127;
    float mu = stats[c] * inv_n;
    float var = stats[CH + c] * inv_n - mu * mu;
    float rs = rsqrtf(var + 1e-5f);
    float val = (h[t] - mu) * rs * g[c] + be[c];
    h[t] = fmaxf(val, 0.0f);
  }
}

// ---------------- edge MLP: out = relu(concat(h[u],h[v],ef)@W1+bm1)@W2+bm2 ----
// block = 256 threads, 32 edges per block.
// er staged TRANSPOSED er[k][edge] with stride 33 (conflict-free staging writes
// (k+e)%32 distinct, conflict-free main-loop reads). 4 edges x 4 cols register
// blocking: per k, 1 float4 W1 load (L2-hot) + 4 LDS b32 + 16 FMA.
__global__ __launch_bounds__(256) void k_edge_mlp(
    const float* __restrict__ h2, const int* __restrict__ u, const int* __restrict__ v,
    const float* __restrict__ ef, const float* __restrict__ W1,
    const float* __restrict__ bm1, const float* __restrict__ W2,
    const float* __restrict__ bm2, float* __restrict__ out) {
  __shared__ float er[2 * CH + CEIN][33];   // [272][33]
  __shared__ float hid[32][132];
  int tid = threadIdx.x;
  int e0 = blockIdx.x * 32;

  // stage h2[u] and h2[v] parts (coalesced 64-lane row reads)
  for (int i = tid; i < 32 * CH; i += 256) {
    int e = i >> 7, k = i & 127;
    er[k][e]      = h2[(long long)u[e0 + e] * CH + k];
    er[CH + k][e] = h2[(long long)v[e0 + e] * CH + k];
  }
  // stage e_feat part
  for (int i = tid; i < 32 * CEIN; i += 256) {
    int e = i >> 4, k = i & 15;
    er[2 * CH + k][e] = ef[(long long)(e0 + e) * CEIN + k];
  }
  __syncthreads();

  // main GEMM: hidden[32][128]
  int c0 = (tid & 31) * 4;
  int eg0 = (tid >> 5) * 4;
  float acc[4][4];
#pragma unroll
  for (int i = 0; i < 4; i++)
#pragma unroll
    for (int j = 0; j < 4; j++) acc[i][j] = bm1[c0 + j];

  for (int k = 0; k < 2 * CH + CEIN; k++) {
    float4 w = *reinterpret_cast<const float4*>(&W1[k * CMH + c0]);
    float a0 = er[k][eg0 + 0];
    float a1 = er[k][eg0 + 1];
    float a2 = er[k][eg0 + 2];
    float a3 = er[k][eg0 + 3];
    acc[0][0] = fmaf(a0, w.x, acc[0][0]);
    acc[0][1] = fmaf(a0, w.y, acc[0][1]);
    acc[0][2] = fmaf(a0, w.z, acc[0][2]);
    acc[0][3] = fmaf(a0, w.w, acc[0][3]);
    acc[1][0] = fmaf(a1, w.x, acc[1][0]);
    acc[1][1] = fmaf(a1, w.y, acc[1][1]);
    acc[1][2] = fmaf(a1, w.z, acc[1][2]);
    acc[1][3] = fmaf(a1, w.w, acc[1][3]);
    acc[2][0] = fmaf(a2, w.x, acc[2][0]);
    acc[2][1] = fmaf(a2, w.y, acc[2][1]);
    acc[2][2] = fmaf(a2, w.z, acc[2][2]);
    acc[2][3] = fmaf(a2, w.w, acc[2][3]);
    acc[3][0] = fmaf(a3, w.x, acc[3][0]);
    acc[3][1] = fmaf(a3, w.y, acc[3][1]);
    acc[3][2] = fmaf(a3, w.z, acc[3][2]);
    acc[3][3] = fmaf(a3, w.w, acc[3][3]);
  }
#pragma unroll
  for (int i = 0; i < 4; i++)
#pragma unroll
    for (int j = 0; j < 4; j++)
      hid[eg0 + i][c0 + j] = fmaxf(acc[i][j], 0.0f);
  __syncthreads();

  // second matmul: out[e][0..7]
  int e = tid >> 3, c = tid & 7;
  float o = bm2[c];
  for (int k = 0; k < CMH; k++) o = fmaf(hid[e][k], W2[k * CNCLS + c], o);
  out[(long long)(e0 + e) * CNCLS + c] = o;
}

// ---------------- launch ----------------
extern "C" void kernel_launch(void* const* d_in, const int* in_sizes, int n_in,
                              void* d_out, int out_size, void* d_ws, size_t ws_size,
                              hipStream_t stream) {
  const float* x_nodes = (const float*)d_in[0];
  const int*   src0    = (const int*)d_in[1];
  const int*   dst0    = (const int*)d_in[2];
  const int*   src1    = (const int*)d_in[3];
  const int*   dst1    = (const int*)d_in[4];
  const int*   u       = (const int*)d_in[5];
  const int*   v       = (const int*)d_in[6];
  const float* e_feat  = (const float*)d_in[7];
  const float* Ws0     = (const float*)d_in[8];
  const float* Wn0     = (const float*)d_in[9];
  const float* b0      = (const float*)d_in[10];
  const float* g0      = (const float*)d_in[11];
  const float* be0     = (const float*)d_in[12];
  const float* Ws1     = (const float*)d_in[13];
  const float* Wn1     = (const float*)d_in[14];
  const float* b1      = (const float*)d_in[15];
  const float* g1      = (const float*)d_in[16];
  const float* be1     = (const float*)d_in[17];
  const float* W1      = (const float*)d_in[18];
  const float* bm1     = (const float*)d_in[19];
  const float* W2      = (const float*)d_in[20];
  const float* bm2     = (const float*)d_in[21];
  float* out = (float*)d_out;

  float* ws  = (float*)d_ws;
  float* agg = ws;                 // 6,400,000 floats (reused layer0/layer1)
  float* deg = ws + 6400000;       // 100,000
  float* h1  = ws + 6500000;       // 12,800,000
  float* h2  = ws + 19300000;      // 6,400,000
  float* s0  = ws + 25700000;      // 256
  float* s1  = ws + 25700256;      // 256

  // ---- layer 0 ----
  hipMemsetAsync(agg, 0, (size_t)CN1 * CIN * sizeof(float), stream);
  hipMemsetAsync(deg, 0, (size_t)CN1 * sizeof(float), stream);
  hipMemsetAsync(s0, 0, 512 * sizeof(float), stream);
  {
    int total = CE0 * CIN;  // 102.4M
    k_scatter<6><<<(total + 255) / 256, 256, 0, stream>>>(x_nodes, src0, dst0, agg, deg, CE0);
  }
  k_sage<CIN, 4><<<CN1 / 4, 128, 0, stream>>>(x_nodes, agg, deg, Ws0, Wn0, b0, h1);
  k_colstats<<<512, 256, 0, stream>>>(h1, CN1, s0);
  k_bnrelu<<<2048, 256, 0, stream>>>(h1, CN1, s0, g0, be0);

  // ---- layer 1 ----
  hipMemsetAsync(agg, 0, (size_t)CN2 * CH * sizeof(float), stream);
  hipMemsetAsync(deg, 0, (size_t)CN2 * sizeof(float), stream);
  {
    int total = CE1 * CH;  // 102.4M
    k_scatter<7><<<(total + 255) / 256, 256, 0, stream>>>(h1, src1, dst1, agg, deg, CE1);
  }
  k_sage<CH, 8><<<CN2 / 8, 128, 0, stream>>>(h1, agg, deg, Ws1, Wn1, b1, h2);
  k_colstats<<<512, 256, 0, stream>>>(h2, CN2, s1);
  k_bnrelu<<<2048, 256, 0, stream>>>(h2, CN2, s1, g1, be1);

  // ---- edge MLP ----
  k_edge_mlp<<<CEP / 32, 256, 0, stream>>>(h2, u, v, e_feat, W1, bm1, W2, bm2, out);
}

// Round 2
// 1682.521 us; speedup vs baseline: 1.2955x; 1.2955x over previous
//
#include <hip/hip_runtime.h>
#include <hip/hip_bf16.h>

#define CN0 200000
#define CN1 100000
#define CN2 50000
#define CE0 1600000
#define CE1 800000
#define CEP 500000
#define CIN 64
#define CH  128
#define CEIN 16
#define CMH 128
#define CNCLS 8

typedef __bf16 bf16x8 __attribute__((ext_vector_type(8)));
typedef float  f32x4  __attribute__((ext_vector_type(4)));

// ---------------- scatter: agg[dst] += x[src], deg[dst] += 1 ----------------
template<int LOGF>
__global__ void k_scatter(const float* __restrict__ x, const int* __restrict__ src,
                          const int* __restrict__ dst, float* __restrict__ agg,
                          float* __restrict__ deg, int nedges) {
  int t = blockIdx.x * blockDim.x + threadIdx.x;
  int e = t >> LOGF;
  if (e >= nedges) return;
  int lane = t & ((1 << LOGF) - 1);
  int s = src[e], d = dst[e];
  atomicAdd(&agg[((long long)d << LOGF) + lane], x[((long long)s << LOGF) + lane]);
  if (lane == 0) atomicAdd(&deg[d], 1.0f);
}

// ---------------- SAGE layer: out = x@Ws + (agg/deg)@Wn + b ----------------
template<int K, int ROWS>
__global__ __launch_bounds__(128) void k_sage(
    const float* __restrict__ x, const float* __restrict__ agg,
    const float* __restrict__ deg,
    const float* __restrict__ Ws, const float* __restrict__ Wn,
    const float* __restrict__ b, float* __restrict__ out) {
  int c = threadIdx.x;              // 0..127
  int r0 = blockIdx.x * ROWS;
  float acc[ROWS], invd[ROWS];
  float bias = b[c];
#pragma unroll
  for (int i = 0; i < ROWS; i++) {
    acc[i] = bias;
    invd[i] = 1.0f / fmaxf(deg[r0 + i], 1.0f);
  }
  for (int k = 0; k < K; k++) {
    float ws = Ws[k * CH + c];
    float wn = Wn[k * CH + c];
#pragma unroll
    for (int i = 0; i < ROWS; i++) {
      acc[i] = fmaf(x[(long long)(r0 + i) * K + k], ws, acc[i]);
      acc[i] = fmaf(agg[(long long)(r0 + i) * K + k] * invd[i], wn, acc[i]);
    }
  }
#pragma unroll
  for (int i = 0; i < ROWS; i++) out[(long long)(r0 + i) * CH + c] = acc[i];
}

// ---------------- column stats ----------------
__global__ void k_colstats(const float* __restrict__ h, int nrows,
                           float* __restrict__ stats) {
  int c = threadIdx.x & 127;
  int sub = threadIdx.x >> 7;
  int rpb = blockDim.x >> 7;
  int r = blockIdx.x * rpb + sub;
  int rstep = gridDim.x * rpb;
  float s = 0.f, ss = 0.f;
  for (; r < nrows; r += rstep) {
    float v = h[(long long)r * CH + c];
    s += v;
    ss = fmaf(v, v, ss);
  }
  atomicAdd(&stats[c], s);
  atomicAdd(&stats[CH + c], ss);
}

// ---------------- BN + ReLU, in place ----------------
__global__ void k_bnrelu(float* __restrict__ h, int nrows,
                         const float* __restrict__ stats,
                         const float* __restrict__ g, const float* __restrict__ be) {
  int total = nrows * CH;
  float inv_n = 1.0f / (float)nrows;
  for (int t = blockIdx.x * blockDim.x + threadIdx.x; t < total;
       t += gridDim.x * blockDim.x) {
    int c = t & 127;
    float mu = stats[c] * inv_n;
    float var = stats[CH + c] * inv_n - mu * mu;
    float rs = rsqrtf(var + 1e-5f);
    float val = (h[t] - mu) * rs * g[c] + be[c];
    h[t] = fmaxf(val, 0.0f);
  }
}

// ---------------- fp32 -> bf16 convert ----------------
__global__ void k_f2b(const float* __restrict__ src, __hip_bfloat16* __restrict__ dst, int n) {
  for (int i = blockIdx.x * blockDim.x + threadIdx.x; i < n; i += gridDim.x * blockDim.x)
    dst[i] = __float2bfloat16(src[i]);
}

// ---------------- W1 -> transposed bf16 [128][272] ----------------
__global__ void k_w1t(const float* __restrict__ W1, __hip_bfloat16* __restrict__ w1t) {
  int t = blockIdx.x * blockDim.x + threadIdx.x;
  if (t >= CMH * (2 * CH + CEIN)) return;
  int n = t / (2 * CH + CEIN), k = t % (2 * CH + CEIN);
  w1t[n * (2 * CH + CEIN) + k] = __float2bfloat16(W1[k * CMH + n]);
}

// ---------------- edge MLP via bf16 MFMA ----------------
// 64 edges/block, 4 waves: wave (wm,wn) computes edges [wm*32,+32) x cols [wn*64,+64).
// A (concat rows) gathered directly from global bf16; B from L2-hot W1T bf16.
// K = 272 = 8*32 + half-masked step (lanes lk>=2 contribute zeros).
__global__ __launch_bounds__(256) void k_edge_mfma(
    const __hip_bfloat16* __restrict__ h2b, const int* __restrict__ u,
    const int* __restrict__ v, const __hip_bfloat16* __restrict__ efb,
    const __hip_bfloat16* __restrict__ w1t, const float* __restrict__ bm1,
    const float* __restrict__ W2, const float* __restrict__ bm2,
    float* __restrict__ out) {
  __shared__ float hid[64][132];
  int tid = threadIdx.x;
  int lane = tid & 63;
  int w = tid >> 6;
  int wm = w & 1;
  int wn = w >> 1;
  int l15 = lane & 15, lk = lane >> 4;
  int e0 = blockIdx.x * 64;

  int eA = e0 + wm * 32 + l15;
  int eB = eA + 16;
  int eAc = min(eA, CEP - 1), eBc = min(eB, CEP - 1);
  int uA = u[eAc], uB = u[eBc], vA = v[eAc], vB = v[eBc];

  const __hip_bfloat16* auP = h2b + (long long)uA * CH + lk * 8;
  const __hip_bfloat16* buP = h2b + (long long)uB * CH + lk * 8;
  const __hip_bfloat16* avP = h2b + (long long)vA * CH + lk * 8;
  const __hip_bfloat16* bvP = h2b + (long long)vB * CH + lk * 8;
  const __hip_bfloat16* aeP = efb + (long long)eAc * CEIN + lk * 8;  // valid lk<2
  const __hip_bfloat16* beP = efb + (long long)eBc * CEIN + lk * 8;

  const __hip_bfloat16* wb[4];
#pragma unroll
  for (int nf = 0; nf < 4; nf++)
    wb[nf] = w1t + (long long)(wn * 64 + nf * 16 + l15) * (2 * CH + CEIN) + lk * 8;

  f32x4 acc[2][4];
#pragma unroll
  for (int nf = 0; nf < 4; nf++) {
    float bias = bm1[wn * 64 + nf * 16 + l15];
#pragma unroll
    for (int m = 0; m < 2; m++) {
      acc[m][nf][0] = bias; acc[m][nf][1] = bias;
      acc[m][nf][2] = bias; acc[m][nf][3] = bias;
    }
  }

  bf16x8 zf = {};

#pragma unroll
  for (int kk = 0; kk < 9; kk++) {
    bf16x8 a0, a1;
    if (kk < 4) {
      a0 = *reinterpret_cast<const bf16x8*>(auP + kk * 32);
      a1 = *reinterpret_cast<const bf16x8*>(buP + kk * 32);
    } else if (kk < 8) {
      a0 = *reinterpret_cast<const bf16x8*>(avP + (kk - 4) * 32);
      a1 = *reinterpret_cast<const bf16x8*>(bvP + (kk - 4) * 32);
    } else {
      a0 = (lk < 2) ? *reinterpret_cast<const bf16x8*>(aeP) : zf;
      a1 = (lk < 2) ? *reinterpret_cast<const bf16x8*>(beP) : zf;
    }
#pragma unroll
    for (int nf = 0; nf < 4; nf++) {
      bf16x8 b;
      if (kk < 8) b = *reinterpret_cast<const bf16x8*>(wb[nf] + kk * 32);
      else        b = (lk < 2) ? *reinterpret_cast<const bf16x8*>(wb[nf] + 256) : zf;
      acc[0][nf] = __builtin_amdgcn_mfma_f32_16x16x32_bf16(a0, b, acc[0][nf], 0, 0, 0);
      acc[1][nf] = __builtin_amdgcn_mfma_f32_16x16x32_bf16(a1, b, acc[1][nf], 0, 0, 0);
    }
  }

  // ReLU -> LDS hidden tile
#pragma unroll
  for (int m = 0; m < 2; m++)
#pragma unroll
    for (int nf = 0; nf < 4; nf++)
#pragma unroll
      for (int r = 0; r < 4; r++) {
        int row = wm * 32 + m * 16 + lk * 4 + r;
        int col = wn * 64 + nf * 16 + l15;
        hid[row][col] = fmaxf(acc[m][nf][r], 0.0f);
      }
  __syncthreads();

  // GEMM2: out[e][0..7] = relu_hid[e] @ W2 + bm2
#pragma unroll
  for (int i = tid; i < 64 * CNCLS; i += 256) {
    int e = i >> 3, c = i & 7;
    if (e0 + e >= CEP) continue;
    float o = bm2[c];
    const float4* hp = reinterpret_cast<const float4*>(&hid[e][0]);
#pragma unroll
    for (int k4 = 0; k4 < 32; k4++) {
      float4 hv = hp[k4];
      o = fmaf(hv.x, W2[(k4 * 4 + 0) * CNCLS + c], o);
      o = fmaf(hv.y, W2[(k4 * 4 + 1) * CNCLS + c], o);
      o = fmaf(hv.z, W2[(k4 * 4 + 2) * CNCLS + c], o);
      o = fmaf(hv.w, W2[(k4 * 4 + 3) * CNCLS + c], o);
    }
    out[(long long)(e0 + e) * CNCLS + c] = o;
  }
}

// ---------------- launch ----------------
extern "C" void kernel_launch(void* const* d_in, const int* in_sizes, int n_in,
                              void* d_out, int out_size, void* d_ws, size_t ws_size,
                              hipStream_t stream) {
  const float* x_nodes = (const float*)d_in[0];
  const int*   src0    = (const int*)d_in[1];
  const int*   dst0    = (const int*)d_in[2];
  const int*   src1    = (const int*)d_in[3];
  const int*   dst1    = (const int*)d_in[4];
  const int*   u       = (const int*)d_in[5];
  const int*   v       = (const int*)d_in[6];
  const float* e_feat  = (const float*)d_in[7];
  const float* Ws0     = (const float*)d_in[8];
  const float* Wn0     = (const float*)d_in[9];
  const float* b0      = (const float*)d_in[10];
  const float* g0      = (const float*)d_in[11];
  const float* be0     = (const float*)d_in[12];
  const float* Ws1     = (const float*)d_in[13];
  const float* Wn1     = (const float*)d_in[14];
  const float* b1      = (const float*)d_in[15];
  const float* g1      = (const float*)d_in[16];
  const float* be1     = (const float*)d_in[17];
  const float* W1      = (const float*)d_in[18];
  const float* bm1     = (const float*)d_in[19];
  const float* W2      = (const float*)d_in[20];
  const float* bm2     = (const float*)d_in[21];
  float* out = (float*)d_out;

  float* ws  = (float*)d_ws;
  float* agg = ws;                 // 6.4M floats (layer0/layer1; later efb)
  float* deg = ws + 6400000;       // 100K
  float* h1  = ws + 6500000;       // 12.8M (later h2b + w1t)
  float* h2  = ws + 19300000;      // 6.4M fp32
  float* s0  = ws + 25700000;      // 256
  float* s1  = ws + 25700256;      // 256

  // aliases (regions free by the time they're written)
  __hip_bfloat16* efb  = (__hip_bfloat16*)agg;            // 500K*16 bf16 = 4M floats
  __hip_bfloat16* h2b  = (__hip_bfloat16*)h1;             // 50K*128 bf16 = 3.2M floats
  __hip_bfloat16* w1tb = (__hip_bfloat16*)(h1 + 6500000); // 128*272 bf16

  // ---- layer 0 ----
  hipMemsetAsync(agg, 0, (size_t)CN1 * CIN * sizeof(float), stream);
  hipMemsetAsync(deg, 0, (size_t)CN1 * sizeof(float), stream);
  hipMemsetAsync(s0, 0, 512 * sizeof(float), stream);
  {
    int total = CE0 * CIN;
    k_scatter<6><<<(total + 255) / 256, 256, 0, stream>>>(x_nodes, src0, dst0, agg, deg, CE0);
  }
  k_sage<CIN, 4><<<CN1 / 4, 128, 0, stream>>>(x_nodes, agg, deg, Ws0, Wn0, b0, h1);
  k_colstats<<<512, 256, 0, stream>>>(h1, CN1, s0);
  k_bnrelu<<<2048, 256, 0, stream>>>(h1, CN1, s0, g0, be0);

  // ---- layer 1 ----
  hipMemsetAsync(agg, 0, (size_t)CN2 * CH * sizeof(float), stream);
  hipMemsetAsync(deg, 0, (size_t)CN2 * sizeof(float), stream);
  {
    int total = CE1 * CH;
    k_scatter<7><<<(total + 255) / 256, 256, 0, stream>>>(h1, src1, dst1, agg, deg, CE1);
  }
  k_sage<CH, 8><<<CN2 / 8, 128, 0, stream>>>(h1, agg, deg, Ws1, Wn1, b1, h2);
  k_colstats<<<512, 256, 0, stream>>>(h2, CN2, s1);
  k_bnrelu<<<2048, 256, 0, stream>>>(h2, CN2, s1, g1, be1);

  // ---- bf16 conversions (h1/agg regions now free) ----
  k_f2b<<<2048, 256, 0, stream>>>(h2, h2b, CN2 * CH);
  k_f2b<<<2048, 256, 0, stream>>>(e_feat, efb, CEP * CEIN);
  k_w1t<<<(CMH * (2 * CH + CEIN) + 255) / 256, 256, 0, stream>>>(W1, w1tb);

  // ---- edge MLP (MFMA) ----
  k_edge_mfma<<<(CEP + 63) / 64, 256, 0, stream>>>(h2b, u, v, efb, w1tb, bm1, W2, bm2, out);
}

// Round 4
// 1225.859 us; speedup vs baseline: 1.7781x; 1.3725x over previous
//
#include <hip/hip_runtime.h>
#include <hip/hip_bf16.h>

#define CN0 200000
#define CN1 100000
#define CN2 50000
#define CE0 1600000
#define CE1 800000
#define CEP 500000
#define CIN 64
#define CH  128
#define CEIN 16
#define CMH 128
#define CNCLS 8

typedef __bf16 bf16x8 __attribute__((ext_vector_type(8)));
typedef float  f32x4  __attribute__((ext_vector_type(4)));

// ---------------- histogram: cnt[dst[e]]++ ----------------
__global__ void k_hist(const int* __restrict__ dst, int n, int* __restrict__ cnt) {
  int i = blockIdx.x * blockDim.x + threadIdx.x;
  if (i < n) atomicAdd(&cnt[dst[i]], 1);
}

// ---------------- scan phase 1: per-1024-block exclusive scan ----------------
__global__ __launch_bounds__(256) void k_scan1(const int* __restrict__ cnt, int n,
                                               int* __restrict__ excl, int* __restrict__ bsum) {
  __shared__ int sh[256];
  int t = threadIdx.x;
  int base = blockIdx.x * 1024 + t * 4;
  int v[4];
#pragma unroll
  for (int i = 0; i < 4; i++) v[i] = (base + i < n) ? cnt[base + i] : 0;
  int tsum = v[0] + v[1] + v[2] + v[3];
  sh[t] = tsum; __syncthreads();
  for (int ofs = 1; ofs < 256; ofs <<= 1) {
    int x = (t >= ofs) ? sh[t - ofs] : 0; __syncthreads();
    sh[t] += x; __syncthreads();
  }
  int run = sh[t] - tsum;
  if (t == 255) bsum[blockIdx.x] = sh[255];
#pragma unroll
  for (int i = 0; i < 4; i++) {
    if (base + i < n) excl[base + i] = run;
    run += v[i];
  }
}

// ---------------- scan phase 2: exclusive scan of block sums (n<=256) ----------------
__global__ __launch_bounds__(256) void k_scan2(int* __restrict__ bsum, int n) {
  __shared__ int sh[256];
  int t = threadIdx.x;
  int v = (t < n) ? bsum[t] : 0;
  sh[t] = v; __syncthreads();
  for (int ofs = 1; ofs < 256; ofs <<= 1) {
    int x = (t >= ofs) ? sh[t - ofs] : 0; __syncthreads();
    sh[t] += x; __syncthreads();
  }
  if (t < n) bsum[t] = sh[t] - v;
}

// ---------------- scan phase 3: add block offsets, emit off & cur ----------------
__global__ void k_scan3(int* __restrict__ off, int* __restrict__ cur,
                        const int* __restrict__ bsum, int n, int total) {
  int i = blockIdx.x * blockDim.x + threadIdx.x;
  if (i < n) {
    int vv = off[i] + bsum[i >> 10];
    off[i] = vv; cur[i] = vv;
  }
  if (i == n) off[n] = total;
}

// ---------------- reorder: srcs[pos++] = src[e], bucketed by dst ----------------
__global__ void k_reorder(const int* __restrict__ src, const int* __restrict__ dst,
                          int n, int* __restrict__ cur, int* __restrict__ srcs) {
  int i = blockIdx.x * blockDim.x + threadIdx.x;
  if (i < n) {
    int p = atomicAdd(&cur[dst[i]], 1);
    srcs[p] = src[i];
  }
}

// ---------------- gather-mean, 64-wide features (one wave per node) ----------------
__global__ __launch_bounds__(256) void k_gather64(
    const __hip_bfloat16* __restrict__ xb, const int* __restrict__ off,
    const int* __restrict__ srcs, float* __restrict__ mean, int nnodes) {
  int node = blockIdx.x * 4 + (threadIdx.x >> 6);
  if (node >= nnodes) return;
  int lane = threadIdx.x & 63;
  int s = off[node], e = off[node + 1];
  float acc = 0.f;
  int p = s;
  for (; p + 1 < e; p += 2) {
    int s0 = srcs[p], s1 = srcs[p + 1];
    float a = __bfloat162float(xb[(long long)s0 * CIN + lane]);
    float b = __bfloat162float(xb[(long long)s1 * CIN + lane]);
    acc += a + b;
  }
  if (p < e) acc += __bfloat162float(xb[(long long)srcs[p] * CIN + lane]);
  mean[(long long)node * CIN + lane] = acc / (float)max(e - s, 1);
}

// ---------------- gather-mean, 128-wide features (two waves per node) ----------------
__global__ __launch_bounds__(256) void k_gather128(
    const __hip_bfloat16* __restrict__ hb, const int* __restrict__ off,
    const int* __restrict__ srcs, float* __restrict__ mean, int nnodes) {
  int node = blockIdx.x * 2 + (threadIdx.x >> 7);
  if (node >= nnodes) return;
  int lane = threadIdx.x & 127;
  int s = off[node], e = off[node + 1];
  float acc = 0.f;
  int p = s;
  for (; p + 1 < e; p += 2) {
    int s0 = srcs[p], s1 = srcs[p + 1];
    float a = __bfloat162float(hb[(long long)s0 * CH + lane]);
    float b = __bfloat162float(hb[(long long)s1 * CH + lane]);
    acc += a + b;
  }
  if (p < e) acc += __bfloat162float(hb[(long long)srcs[p] * CH + lane]);
  mean[(long long)node * CH + lane] = acc / (float)max(e - s, 1);
}

// ---------------- SAGE layer: out = x@Ws + mean@Wn + b ----------------
template<int K, int ROWS>
__global__ __launch_bounds__(128) void k_sage(
    const float* __restrict__ x, const float* __restrict__ mean,
    const float* __restrict__ Ws, const float* __restrict__ Wn,
    const float* __restrict__ b, float* __restrict__ out) {
  int c = threadIdx.x;              // 0..127
  int r0 = blockIdx.x * ROWS;
  float acc[ROWS];
  float bias = b[c];
#pragma unroll
  for (int i = 0; i < ROWS; i++) acc[i] = bias;
  for (int k = 0; k < K; k++) {
    float ws = Ws[k * CH + c];
    float wn = Wn[k * CH + c];
#pragma unroll
    for (int i = 0; i < ROWS; i++) {
      acc[i] = fmaf(x[(long long)(r0 + i) * K + k], ws, acc[i]);
      acc[i] = fmaf(mean[(long long)(r0 + i) * K + k], wn, acc[i]);
    }
  }
#pragma unroll
  for (int i = 0; i < ROWS; i++) out[(long long)(r0 + i) * CH + c] = acc[i];
}

// ---------------- column stats ----------------
__global__ void k_colstats(const float* __restrict__ h, int nrows,
                           float* __restrict__ stats) {
  int c = threadIdx.x & 127;
  int sub = threadIdx.x >> 7;
  int rpb = blockDim.x >> 7;
  int r = blockIdx.x * rpb + sub;
  int rstep = gridDim.x * rpb;
  float s = 0.f, ss = 0.f;
  for (; r < nrows; r += rstep) {
    float v = h[(long long)r * CH + c];
    s += v;
    ss = fmaf(v, v, ss);
  }
  atomicAdd(&stats[c], s);
  atomicAdd(&stats[CH + c], ss);
}

// ---------------- BN + ReLU, in place ----------------
__global__ void k_bnrelu(float* __restrict__ h, int nrows,
                         const float* __restrict__ stats,
                         const float* __restrict__ g, const float* __restrict__ be) {
  int total = nrows * CH;
  float inv_n = 1.0f / (float)nrows;
  for (int t = blockIdx.x * blockDim.x + threadIdx.x; t < total;
       t += gridDim.x * blockDim.x) {
    int c = t & 127;
    float mu = stats[c] * inv_n;
    float var = stats[CH + c] * inv_n - mu * mu;
    float rs = rsqrtf(var + 1e-5f);
    float val = (h[t] - mu) * rs * g[c] + be[c];
    h[t] = fmaxf(val, 0.0f);
  }
}

// ---------------- fp32 -> bf16 convert ----------------
__global__ void k_f2b(const float* __restrict__ src, __hip_bfloat16* __restrict__ dst, int n) {
  for (int i = blockIdx.x * blockDim.x + threadIdx.x; i < n; i += gridDim.x * blockDim.x)
    dst[i] = __float2bfloat16(src[i]);
}

// ---------------- W1 -> transposed bf16 [128][272] ----------------
__global__ void k_w1t(const float* __restrict__ W1, __hip_bfloat16* __restrict__ w1t) {
  int t = blockIdx.x * blockDim.x + threadIdx.x;
  if (t >= CMH * (2 * CH + CEIN)) return;
  int n = t / (2 * CH + CEIN), k = t % (2 * CH + CEIN);
  w1t[n * (2 * CH + CEIN) + k] = __float2bfloat16(W1[k * CMH + n]);
}

// ---------------- edge MLP via bf16 MFMA ----------------
__global__ __launch_bounds__(256) void k_edge_mfma(
    const __hip_bfloat16* __restrict__ h2b, const int* __restrict__ u,
    const int* __restrict__ v, const __hip_bfloat16* __restrict__ efb,
    const __hip_bfloat16* __restrict__ w1t, const float* __restrict__ bm1,
    const float* __restrict__ W2, const float* __restrict__ bm2,
    float* __restrict__ out) {
  __shared__ float hid[64][132];
  int tid = threadIdx.x;
  int lane = tid & 63;
  int w = tid >> 6;
  int wm = w & 1;
  int wn = w >> 1;
  int l15 = lane & 15, lk = lane >> 4;
  int e0 = blockIdx.x * 64;

  int eA = e0 + wm * 32 + l15;
  int eB = eA + 16;
  int eAc = min(eA, CEP - 1), eBc = min(eB, CEP - 1);
  int uA = u[eAc], uB = u[eBc], vA = v[eAc], vB = v[eBc];

  const __hip_bfloat16* auP = h2b + (long long)uA * CH + lk * 8;
  const __hip_bfloat16* buP = h2b + (long long)uB * CH + lk * 8;
  const __hip_bfloat16* avP = h2b + (long long)vA * CH + lk * 8;
  const __hip_bfloat16* bvP = h2b + (long long)vB * CH + lk * 8;
  const __hip_bfloat16* aeP = efb + (long long)eAc * CEIN + lk * 8;  // valid lk<2
  const __hip_bfloat16* beP = efb + (long long)eBc * CEIN + lk * 8;

  const __hip_bfloat16* wb[4];
#pragma unroll
  for (int nf = 0; nf < 4; nf++)
    wb[nf] = w1t + (long long)(wn * 64 + nf * 16 + l15) * (2 * CH + CEIN) + lk * 8;

  f32x4 acc[2][4];
#pragma unroll
  for (int nf = 0; nf < 4; nf++) {
    float bias = bm1[wn * 64 + nf * 16 + l15];
#pragma unroll
    for (int m = 0; m < 2; m++) {
      acc[m][nf][0] = bias; acc[m][nf][1] = bias;
      acc[m][nf][2] = bias; acc[m][nf][3] = bias;
    }
  }

  bf16x8 zf = {};

#pragma unroll
  for (int kk = 0; kk < 9; kk++) {
    bf16x8 a0, a1;
    if (kk < 4) {
      a0 = *reinterpret_cast<const bf16x8*>(auP + kk * 32);
      a1 = *reinterpret_cast<const bf16x8*>(buP + kk * 32);
    } else if (kk < 8) {
      a0 = *reinterpret_cast<const bf16x8*>(avP + (kk - 4) * 32);
      a1 = *reinterpret_cast<const bf16x8*>(bvP + (kk - 4) * 32);
    } else {
      a0 = (lk < 2) ? *reinterpret_cast<const bf16x8*>(aeP) : zf;
      a1 = (lk < 2) ? *reinterpret_cast<const bf16x8*>(beP) : zf;
    }
#pragma unroll
    for (int nf = 0; nf < 4; nf++) {
      bf16x8 b;
      if (kk < 8) b = *reinterpret_cast<const bf16x8*>(wb[nf] + kk * 32);
      else        b = (lk < 2) ? *reinterpret_cast<const bf16x8*>(wb[nf] + 256) : zf;
      acc[0][nf] = __builtin_amdgcn_mfma_f32_16x16x32_bf16(a0, b, acc[0][nf], 0, 0, 0);
      acc[1][nf] = __builtin_amdgcn_mfma_f32_16x16x32_bf16(a1, b, acc[1][nf], 0, 0, 0);
    }
  }

#pragma unroll
  for (int m = 0; m < 2; m++)
#pragma unroll
    for (int nf = 0; nf < 4; nf++)
#pragma unroll
      for (int r = 0; r < 4; r++) {
        int row = wm * 32 + m * 16 + lk * 4 + r;
        int col = wn * 64 + nf * 16 + l15;
        hid[row][col] = fmaxf(acc[m][nf][r], 0.0f);
      }
  __syncthreads();

#pragma unroll
  for (int i = tid; i < 64 * CNCLS; i += 256) {
    int e = i >> 3, c = i & 7;
    if (e0 + e >= CEP) continue;
    float o = bm2[c];
    const float4* hp = reinterpret_cast<const float4*>(&hid[e][0]);
#pragma unroll
    for (int k4 = 0; k4 < 32; k4++) {
      float4 hv = hp[k4];
      o = fmaf(hv.x, W2[(k4 * 4 + 0) * CNCLS + c], o);
      o = fmaf(hv.y, W2[(k4 * 4 + 1) * CNCLS + c], o);
      o = fmaf(hv.z, W2[(k4 * 4 + 2) * CNCLS + c], o);
      o = fmaf(hv.w, W2[(k4 * 4 + 3) * CNCLS + c], o);
    }
    out[(long long)(e0 + e) * CNCLS + c] = o;
  }
}

// ---------------- launch ----------------
extern "C" void kernel_launch(void* const* d_in, const int* in_sizes, int n_in,
                              void* d_out, int out_size, void* d_ws, size_t ws_size,
                              hipStream_t stream) {
  const float* x_nodes = (const float*)d_in[0];
  const int*   src0    = (const int*)d_in[1];
  const int*   dst0    = (const int*)d_in[2];
  const int*   src1    = (const int*)d_in[3];
  const int*   dst1    = (const int*)d_in[4];
  const int*   u       = (const int*)d_in[5];
  const int*   v       = (const int*)d_in[6];
  const float* e_feat  = (const float*)d_in[7];
  const float* Ws0     = (const float*)d_in[8];
  const float* Wn0     = (const float*)d_in[9];
  const float* b0      = (const float*)d_in[10];
  const float* g0      = (const float*)d_in[11];
  const float* be0     = (const float*)d_in[12];
  const float* Ws1     = (const float*)d_in[13];
  const float* Wn1     = (const float*)d_in[14];
  const float* b1      = (const float*)d_in[15];
  const float* g1      = (const float*)d_in[16];
  const float* be1     = (const float*)d_in[17];
  const float* W1      = (const float*)d_in[18];
  const float* bm1     = (const float*)d_in[19];
  const float* W2      = (const float*)d_in[20];
  const float* bm2     = (const float*)d_in[21];
  float* out = (float*)d_out;

  float* ws   = (float*)d_ws;
  float* aggm = ws;                   // 6.4M floats: mean L0 / mean L1; later efb
  float* h1   = ws + 6400000;         // 12.8M floats; later h2b + w1t
  float* xreg = ws + 19200000;        // 6.4M floats: xb (L0) -> h1b (L1) -> h2 (fp32)
  int*   offA = (int*)(ws + 25600000);  // 100001
  int*   curA = (int*)(ws + 25730000);  // 100000
  int*   cntA = (int*)(ws + 25860000);  // 100000
  int*   bsum = (int*)(ws + 25990000);  // 512
  int*   srcsA= (int*)(ws + 26000000);  // 1.6M
  float* s0   = ws + 27600000;          // 256
  float* s1   = ws + 27600256;          // 256

  __hip_bfloat16* xb   = (__hip_bfloat16*)xreg;            // 200K*64 bf16
  __hip_bfloat16* h1b  = (__hip_bfloat16*)xreg;            // 100K*128 bf16
  float*          h2   = xreg;                              // 50K*128 fp32
  __hip_bfloat16* efb  = (__hip_bfloat16*)aggm;            // 500K*16 bf16
  __hip_bfloat16* h2b  = (__hip_bfloat16*)h1;              // 50K*128 bf16 = 3.2M floats
  __hip_bfloat16* w1tb = (__hip_bfloat16*)(h1 + 6400000);  // AFTER h2b region (fix)

  // ---- layer 0: sort edges by dst ----
  hipMemsetAsync(cntA, 0, CN1 * sizeof(int), stream);
  hipMemsetAsync(s0, 0, 512 * sizeof(float), stream);
  k_hist<<<(CE0 + 255) / 256, 256, 0, stream>>>(dst0, CE0, cntA);
  {
    int nblk = (CN1 + 1023) / 1024;  // 98
    k_scan1<<<nblk, 256, 0, stream>>>(cntA, CN1, offA, bsum);
    k_scan2<<<1, 256, 0, stream>>>(bsum, nblk);
    k_scan3<<<(CN1 + 256) / 256, 256, 0, stream>>>(offA, curA, bsum, CN1, CE0);
  }
  k_reorder<<<(CE0 + 255) / 256, 256, 0, stream>>>(src0, dst0, CE0, curA, srcsA);

  // ---- layer 0: gather-mean + sage + bn ----
  k_f2b<<<2048, 256, 0, stream>>>(x_nodes, xb, CN0 * CIN);
  k_gather64<<<(CN1 + 3) / 4, 256, 0, stream>>>(xb, offA, srcsA, aggm, CN1);
  k_sage<CIN, 4><<<CN1 / 4, 128, 0, stream>>>(x_nodes, aggm, Ws0, Wn0, b0, h1);
  k_colstats<<<512, 256, 0, stream>>>(h1, CN1, s0);
  k_bnrelu<<<2048, 256, 0, stream>>>(h1, CN1, s0, g0, be0);

  // ---- layer 1: sort edges by dst ----
  hipMemsetAsync(cntA, 0, CN2 * sizeof(int), stream);
  k_hist<<<(CE1 + 255) / 256, 256, 0, stream>>>(dst1, CE1, cntA);
  {
    int nblk = (CN2 + 1023) / 1024;  // 49
    k_scan1<<<nblk, 256, 0, stream>>>(cntA, CN2, offA, bsum);
    k_scan2<<<1, 256, 0, stream>>>(bsum, nblk);
    k_scan3<<<(CN2 + 256) / 256, 256, 0, stream>>>(offA, curA, bsum, CN2, CE1);
  }
  k_reorder<<<(CE1 + 255) / 256, 256, 0, stream>>>(src1, dst1, CE1, curA, srcsA);

  // ---- layer 1: gather-mean + sage + bn ----
  k_f2b<<<2048, 256, 0, stream>>>(h1, h1b, CN1 * CH);
  k_gather128<<<(CN2 + 1) / 2, 256, 0, stream>>>(h1b, offA, srcsA, aggm, CN2);
  k_sage<CH, 8><<<CN2 / 8, 128, 0, stream>>>(h1, aggm, Ws1, Wn1, b1, h2);
  k_colstats<<<512, 256, 0, stream>>>(h2, CN2, s1);
  k_bnrelu<<<2048, 256, 0, stream>>>(h2, CN2, s1, g1, be1);

  // ---- edge MLP (MFMA) ----
  k_f2b<<<2048, 256, 0, stream>>>(h2, h2b, CN2 * CH);
  k_f2b<<<2048, 256, 0, stream>>>(e_feat, efb, CEP * CEIN);
  k_w1t<<<(CMH * (2 * CH + CEIN) + 255) / 256, 256, 0, stream>>>(W1, w1tb);
  k_edge_mfma<<<(CEP + 63) / 64, 256, 0, stream>>>(h2b, u, v, efb, w1tb, bm1, W2, bm2, out);
}

// Round 5
// 800.052 us; speedup vs baseline: 2.7244x; 1.5322x over previous
//
#include <hip/hip_runtime.h>
#include <hip/hip_bf16.h>

#define CN0 200000
#define CN1 100000
#define CN2 50000
#define CE0 1600000
#define CE1 800000
#define CEP 500000
#define CIN 64
#define CH  128
#define CEIN 16
#define CMH 128
#define CNCLS 8

typedef __bf16 bf16x8 __attribute__((ext_vector_type(8)));
typedef float  f32x4  __attribute__((ext_vector_type(4)));
typedef unsigned short u16x8 __attribute__((ext_vector_type(8)));
typedef unsigned short u16x4 __attribute__((ext_vector_type(4)));

__device__ inline float b2f(unsigned short u) {
  union { unsigned int i; float f; } x; x.i = ((unsigned int)u) << 16; return x.f;
}
__device__ inline unsigned short f2bu(float f) {
  __hip_bfloat16 h = __float2bfloat16(f);
  return *reinterpret_cast<unsigned short*>(&h);
}

// ---------------- histogram: cnt[dst[e]]++ ----------------
__global__ void k_hist(const int* __restrict__ dst, int n, int* __restrict__ cnt) {
  int i = blockIdx.x * blockDim.x + threadIdx.x;
  if (i < n) atomicAdd(&cnt[dst[i]], 1);
}

// ---------------- scan phase 1 ----------------
__global__ __launch_bounds__(256) void k_scan1(const int* __restrict__ cnt, int n,
                                               int* __restrict__ excl, int* __restrict__ bsum) {
  __shared__ int sh[256];
  int t = threadIdx.x;
  int base = blockIdx.x * 1024 + t * 4;
  int v[4];
#pragma unroll
  for (int i = 0; i < 4; i++) v[i] = (base + i < n) ? cnt[base + i] : 0;
  int tsum = v[0] + v[1] + v[2] + v[3];
  sh[t] = tsum; __syncthreads();
  for (int ofs = 1; ofs < 256; ofs <<= 1) {
    int x = (t >= ofs) ? sh[t - ofs] : 0; __syncthreads();
    sh[t] += x; __syncthreads();
  }
  int run = sh[t] - tsum;
  if (t == 255) bsum[blockIdx.x] = sh[255];
#pragma unroll
  for (int i = 0; i < 4; i++) {
    if (base + i < n) excl[base + i] = run;
    run += v[i];
  }
}

// ---------------- scan phase 2 ----------------
__global__ __launch_bounds__(256) void k_scan2(int* __restrict__ bsum, int n) {
  __shared__ int sh[256];
  int t = threadIdx.x;
  int v = (t < n) ? bsum[t] : 0;
  sh[t] = v; __syncthreads();
  for (int ofs = 1; ofs < 256; ofs <<= 1) {
    int x = (t >= ofs) ? sh[t - ofs] : 0; __syncthreads();
    sh[t] += x; __syncthreads();
  }
  if (t < n) bsum[t] = sh[t] - v;
}

// ---------------- scan phase 3 ----------------
__global__ void k_scan3(int* __restrict__ off, int* __restrict__ cur,
                        const int* __restrict__ bsum, int n, int total) {
  int i = blockIdx.x * blockDim.x + threadIdx.x;
  if (i < n) {
    int vv = off[i] + bsum[i >> 10];
    off[i] = vv; cur[i] = vv;
  }
  if (i == n) off[n] = total;
}

// ---------------- reorder ----------------
__global__ void k_reorder(const int* __restrict__ src, const int* __restrict__ dst,
                          int n, int* __restrict__ cur, int* __restrict__ srcs) {
  int i = blockIdx.x * blockDim.x + threadIdx.x;
  if (i < n) {
    int p = atomicAdd(&cur[dst[i]], 1);
    srcs[p] = src[i];
  }
}

// ---------------- gather-mean 64-wide: 1 node/wave, 8 parallel edges ----------------
__global__ __launch_bounds__(256) void k_gather64b(
    const __hip_bfloat16* __restrict__ xb, const int* __restrict__ off,
    const int* __restrict__ srcs, __hip_bfloat16* __restrict__ meanb, int nnodes) {
  int node = blockIdx.x * 4 + (threadIdx.x >> 6);
  if (node >= nnodes) return;
  int lane = threadIdx.x & 63;
  int g = lane >> 3;            // 8 edge groups
  int f8 = (lane & 7) * 8;      // feature offset
  int s = off[node], e = off[node + 1];
  float acc[8] = {0.f,0.f,0.f,0.f,0.f,0.f,0.f,0.f};
  for (int p = s + g; p < e; p += 8) {
    int sn = srcs[p];
    u16x8 v = *reinterpret_cast<const u16x8*>(xb + (long long)sn * CIN + f8);
#pragma unroll
    for (int j = 0; j < 8; j++) acc[j] += b2f(v[j]);
  }
#pragma unroll
  for (int m = 8; m < 64; m <<= 1)
#pragma unroll
    for (int j = 0; j < 8; j++) acc[j] += __shfl_xor(acc[j], m, 64);
  if (g == 0) {
    float inv = 1.0f / (float)max(e - s, 1);
    u16x8 o;
#pragma unroll
    for (int j = 0; j < 8; j++) o[j] = f2bu(acc[j] * inv);
    *reinterpret_cast<u16x8*>(meanb + (long long)node * CIN + f8) = o;
  }
}

// ---------------- gather-mean 128-wide: 1 node/wave, 4 parallel edges ----------------
__global__ __launch_bounds__(256) void k_gather128b(
    const __hip_bfloat16* __restrict__ hb, const int* __restrict__ off,
    const int* __restrict__ srcs, __hip_bfloat16* __restrict__ meanb, int nnodes) {
  int node = blockIdx.x * 4 + (threadIdx.x >> 6);
  if (node >= nnodes) return;
  int lane = threadIdx.x & 63;
  int g = lane >> 4;            // 4 edge groups
  int f8 = (lane & 15) * 8;     // feature offset
  int s = off[node], e = off[node + 1];
  float acc[8] = {0.f,0.f,0.f,0.f,0.f,0.f,0.f,0.f};
  for (int p = s + g; p < e; p += 4) {
    int sn = srcs[p];
    u16x8 v = *reinterpret_cast<const u16x8*>(hb + (long long)sn * CH + f8);
#pragma unroll
    for (int j = 0; j < 8; j++) acc[j] += b2f(v[j]);
  }
#pragma unroll
  for (int m = 16; m < 64; m <<= 1)
#pragma unroll
    for (int j = 0; j < 8; j++) acc[j] += __shfl_xor(acc[j], m, 64);
  if (g == 0) {
    float inv = 1.0f / (float)max(e - s, 1);
    u16x8 o;
#pragma unroll
    for (int j = 0; j < 8; j++) o[j] = f2bu(acc[j] * inv);
    *reinterpret_cast<u16x8*>(meanb + (long long)node * CH + f8) = o;
  }
}

// ---------------- SAGE layer via MFMA: outb = [A1|A2] @ wT^T + bias (bf16 out) ----
template<int KA>
__global__ __launch_bounds__(256) void k_sage_mfma(
    const __hip_bfloat16* __restrict__ A1, const __hip_bfloat16* __restrict__ A2,
    const __hip_bfloat16* __restrict__ wT, const float* __restrict__ bias,
    __hip_bfloat16* __restrict__ outb, int M) {
  int tid = threadIdx.x;
  int lane = tid & 63;
  int w = tid >> 6;
  int wm = w & 1, wn = w >> 1;
  int l15 = lane & 15, lk = lane >> 4;
  int r0 = blockIdx.x * 64;

  int rA = r0 + wm * 32 + l15;
  int rB = rA + 16;
  int rAc = min(rA, M - 1), rBc = min(rB, M - 1);
  const __hip_bfloat16* a1A = A1 + (long long)rAc * KA + lk * 8;
  const __hip_bfloat16* a1B = A1 + (long long)rBc * KA + lk * 8;
  const __hip_bfloat16* a2A = A2 + (long long)rAc * KA + lk * 8;
  const __hip_bfloat16* a2B = A2 + (long long)rBc * KA + lk * 8;
  const __hip_bfloat16* wp[4];
#pragma unroll
  for (int nf = 0; nf < 4; nf++)
    wp[nf] = wT + (long long)(wn * 64 + nf * 16 + l15) * (2 * KA) + lk * 8;

  f32x4 acc[2][4];
#pragma unroll
  for (int nf = 0; nf < 4; nf++) {
    float bv = bias[wn * 64 + nf * 16 + l15];
#pragma unroll
    for (int m = 0; m < 2; m++) {
      acc[m][nf][0] = bv; acc[m][nf][1] = bv;
      acc[m][nf][2] = bv; acc[m][nf][3] = bv;
    }
  }

  constexpr int HS = KA / 32;
#pragma unroll
  for (int kk = 0; kk < 2 * HS; kk++) {
    bf16x8 a0, a1v;
    if (kk < HS) {
      a0  = *reinterpret_cast<const bf16x8*>(a1A + kk * 32);
      a1v = *reinterpret_cast<const bf16x8*>(a1B + kk * 32);
    } else {
      a0  = *reinterpret_cast<const bf16x8*>(a2A + (kk - HS) * 32);
      a1v = *reinterpret_cast<const bf16x8*>(a2B + (kk - HS) * 32);
    }
#pragma unroll
    for (int nf = 0; nf < 4; nf++) {
      bf16x8 b = *reinterpret_cast<const bf16x8*>(wp[nf] + kk * 32);
      acc[0][nf] = __builtin_amdgcn_mfma_f32_16x16x32_bf16(a0,  b, acc[0][nf], 0, 0, 0);
      acc[1][nf] = __builtin_amdgcn_mfma_f32_16x16x32_bf16(a1v, b, acc[1][nf], 0, 0, 0);
    }
  }

  unsigned short* ob = reinterpret_cast<unsigned short*>(outb);
#pragma unroll
  for (int m = 0; m < 2; m++)
#pragma unroll
    for (int nf = 0; nf < 4; nf++)
#pragma unroll
      for (int r = 0; r < 4; r++) {
        int row = r0 + wm * 32 + m * 16 + lk * 4 + r;
        if (row < M) ob[(long long)row * CH + wn * 64 + nf * 16 + l15] = f2bu(acc[m][nf][r]);
      }
}

// ---------------- column stats over bf16 h ----------------
__global__ __launch_bounds__(256) void k_colstats_b(
    const __hip_bfloat16* __restrict__ h, int nrows, float* __restrict__ stats) {
  int tid = threadIdx.x;
  int lane = tid & 63;
  int wv = tid >> 6;
  int cg = lane & 15;
  float s[8] = {0,0,0,0,0,0,0,0}, ss[8] = {0,0,0,0,0,0,0,0};
  for (int r = blockIdx.x * 16 + (tid >> 4); r < nrows; r += gridDim.x * 16) {
    u16x8 v = *reinterpret_cast<const u16x8*>(h + (long long)r * CH + cg * 8);
#pragma unroll
    for (int j = 0; j < 8; j++) { float f = b2f(v[j]); s[j] += f; ss[j] = fmaf(f, f, ss[j]); }
  }
#pragma unroll
  for (int m = 16; m < 64; m <<= 1)
#pragma unroll
    for (int j = 0; j < 8; j++) { s[j] += __shfl_xor(s[j], m, 64); ss[j] += __shfl_xor(ss[j], m, 64); }
  __shared__ float red[2][4][16][8];
  if (lane < 16) {
#pragma unroll
    for (int j = 0; j < 8; j++) { red[0][wv][lane][j] = s[j]; red[1][wv][lane][j] = ss[j]; }
  }
  __syncthreads();
  if (tid < 128) {
    int c = tid >> 3, j = tid & 7;
    float a = red[0][0][c][j] + red[0][1][c][j] + red[0][2][c][j] + red[0][3][c][j];
    float b = red[1][0][c][j] + red[1][1][c][j] + red[1][2][c][j] + red[1][3][c][j];
    atomicAdd(&stats[c * 8 + j], a);
    atomicAdd(&stats[CH + c * 8 + j], b);
  }
}

// ---------------- BN + ReLU on bf16 h, in place ----------------
__global__ void k_bnrelu_b(__hip_bfloat16* __restrict__ h, int nrows,
                           const float* __restrict__ stats,
                           const float* __restrict__ g, const float* __restrict__ be) {
  int total8 = nrows * (CH / 8);
  float inv_n = 1.0f / (float)nrows;
  for (int i = blockIdx.x * blockDim.x + threadIdx.x; i < total8;
       i += gridDim.x * blockDim.x) {
    int cg = (i & 15) * 8;
    u16x8 v = reinterpret_cast<u16x8*>(h)[i];
    u16x8 o;
#pragma unroll
    for (int j = 0; j < 8; j++) {
      int c = cg + j;
      float mu = stats[c] * inv_n;
      float var = stats[CH + c] * inv_n - mu * mu;
      float rs = rsqrtf(var + 1e-5f);
      float val = (b2f(v[j]) - mu) * rs * g[c] + be[c];
      o[j] = f2bu(fmaxf(val, 0.0f));
    }
    reinterpret_cast<u16x8*>(h)[i] = o;
  }
}

// ---------------- x fp32 -> bf16, vectorized ----------------
__global__ void k_f2b4(const float* __restrict__ src, __hip_bfloat16* __restrict__ dst, int n4) {
  for (int i = blockIdx.x * blockDim.x + threadIdx.x; i < n4; i += gridDim.x * blockDim.x) {
    float4 v = reinterpret_cast<const float4*>(src)[i];
    u16x4 o; o[0] = f2bu(v.x); o[1] = f2bu(v.y); o[2] = f2bu(v.z); o[3] = f2bu(v.w);
    reinterpret_cast<u16x4*>(dst)[i] = o;
  }
}

// ---------------- weight prep: wT0[128][128], wT1[128][256], w1t[128][272] ----------
__global__ void k_prep(const float* __restrict__ Ws0, const float* __restrict__ Wn0,
                       const float* __restrict__ Ws1, const float* __restrict__ Wn1,
                       const float* __restrict__ W1,
                       __hip_bfloat16* __restrict__ wT0, __hip_bfloat16* __restrict__ wT1,
                       __hip_bfloat16* __restrict__ w1t) {
  int t = blockIdx.x * blockDim.x + threadIdx.x;
  if (t < 16384) {
    int n = t >> 7, k = t & 127;
    wT0[t] = __float2bfloat16(k < 64 ? Ws0[k * CH + n] : Wn0[(k - 64) * CH + n]);
    return;
  }
  t -= 16384;
  if (t < 32768) {
    int n = t >> 8, k = t & 255;
    wT1[t] = __float2bfloat16(k < 128 ? Ws1[k * CH + n] : Wn1[(k - 128) * CH + n]);
    return;
  }
  t -= 32768;
  if (t < 34816) {
    int n = t / 272, k = t % 272;
    w1t[t] = __float2bfloat16(W1[k * CMH + n]);
  }
}

// ---------------- edge MLP via bf16 MFMA (bf16 hid LDS, fp32 e_feat in-kernel) ----
__global__ __launch_bounds__(256) void k_edge_mfma(
    const __hip_bfloat16* __restrict__ h2b, const int* __restrict__ u,
    const int* __restrict__ v, const float* __restrict__ ef,
    const __hip_bfloat16* __restrict__ w1t, const float* __restrict__ bm1,
    const float* __restrict__ W2, const float* __restrict__ bm2,
    float* __restrict__ out) {
  __shared__ unsigned short hid[64][136];   // bf16, 17.4 KB
  int tid = threadIdx.x;
  int lane = tid & 63;
  int w = tid >> 6;
  int wm = w & 1;
  int wn = w >> 1;
  int l15 = lane & 15, lk = lane >> 4;
  int e0 = blockIdx.x * 64;

  int eA = e0 + wm * 32 + l15;
  int eB = eA + 16;
  int eAc = min(eA, CEP - 1), eBc = min(eB, CEP - 1);
  int uA = u[eAc], uB = u[eBc], vA = v[eAc], vB = v[eBc];

  const __hip_bfloat16* auP = h2b + (long long)uA * CH + lk * 8;
  const __hip_bfloat16* buP = h2b + (long long)uB * CH + lk * 8;
  const __hip_bfloat16* avP = h2b + (long long)vA * CH + lk * 8;
  const __hip_bfloat16* bvP = h2b + (long long)vB * CH + lk * 8;

  const __hip_bfloat16* wb[4];
#pragma unroll
  for (int nf = 0; nf < 4; nf++)
    wb[nf] = w1t + (long long)(wn * 64 + nf * 16 + l15) * (2 * CH + CEIN) + lk * 8;

  // e_feat fragment (k=256..271), fp32 -> bf16 in-reg; valid lanes lk<2
  bf16x8 zf = {};
  bf16x8 aefA = zf, aefB = zf;
  if (lk < 2) {
    const float* pA = ef + (long long)eAc * CEIN + lk * 8;
    const float* pB = ef + (long long)eBc * CEIN + lk * 8;
    u16x8 ua, ub;
#pragma unroll
    for (int j = 0; j < 8; j++) { ua[j] = f2bu(pA[j]); ub[j] = f2bu(pB[j]); }
    aefA = *reinterpret_cast<bf16x8*>(&ua);
    aefB = *reinterpret_cast<bf16x8*>(&ub);
  }

  f32x4 acc[2][4];
#pragma unroll
  for (int nf = 0; nf < 4; nf++) {
    float bias = bm1[wn * 64 + nf * 16 + l15];
#pragma unroll
    for (int m = 0; m < 2; m++) {
      acc[m][nf][0] = bias; acc[m][nf][1] = bias;
      acc[m][nf][2] = bias; acc[m][nf][3] = bias;
    }
  }

#pragma unroll
  for (int kk = 0; kk < 9; kk++) {
    bf16x8 a0, a1;
    if (kk < 4) {
      a0 = *reinterpret_cast<const bf16x8*>(auP + kk * 32);
      a1 = *reinterpret_cast<const bf16x8*>(buP + kk * 32);
    } else if (kk < 8) {
      a0 = *reinterpret_cast<const bf16x8*>(avP + (kk - 4) * 32);
      a1 = *reinterpret_cast<const bf16x8*>(bvP + (kk - 4) * 32);
    } else {
      a0 = aefA;
      a1 = aefB;
    }
#pragma unroll
    for (int nf = 0; nf < 4; nf++) {
      bf16x8 b;
      if (kk < 8) b = *reinterpret_cast<const bf16x8*>(wb[nf] + kk * 32);
      else        b = (lk < 2) ? *reinterpret_cast<const bf16x8*>(wb[nf] + 256) : zf;
      acc[0][nf] = __builtin_amdgcn_mfma_f32_16x16x32_bf16(a0, b, acc[0][nf], 0, 0, 0);
      acc[1][nf] = __builtin_amdgcn_mfma_f32_16x16x32_bf16(a1, b, acc[1][nf], 0, 0, 0);
    }
  }

#pragma unroll
  for (int m = 0; m < 2; m++)
#pragma unroll
    for (int nf = 0; nf < 4; nf++)
#pragma unroll
      for (int r = 0; r < 4; r++) {
        int row = wm * 32 + m * 16 + lk * 4 + r;
        int col = wn * 64 + nf * 16 + l15;
        hid[row][col] = f2bu(fmaxf(acc[m][nf][r], 0.0f));
      }
  __syncthreads();

  // GEMM2: out[e][0..7] = relu_hid[e] @ W2 + bm2
#pragma unroll
  for (int i = tid; i < 64 * CNCLS; i += 256) {
    int e = i >> 3, c = i & 7;
    if (e0 + e >= CEP) continue;
    float o = bm2[c];
    const u16x8* hp = reinterpret_cast<const u16x8*>(&hid[e][0]);
#pragma unroll
    for (int k8 = 0; k8 < 16; k8++) {
      u16x8 hv = hp[k8];
#pragma unroll
      for (int j = 0; j < 8; j++)
        o = fmaf(b2f(hv[j]), W2[(k8 * 8 + j) * CNCLS + c], o);
    }
    out[(long long)(e0 + e) * CNCLS + c] = o;
  }
}

// ---------------- launch ----------------
extern "C" void kernel_launch(void* const* d_in, const int* in_sizes, int n_in,
                              void* d_out, int out_size, void* d_ws, size_t ws_size,
                              hipStream_t stream) {
  const float* x_nodes = (const float*)d_in[0];
  const int*   src0    = (const int*)d_in[1];
  const int*   dst0    = (const int*)d_in[2];
  const int*   src1    = (const int*)d_in[3];
  const int*   dst1    = (const int*)d_in[4];
  const int*   u       = (const int*)d_in[5];
  const int*   v       = (const int*)d_in[6];
  const float* e_feat  = (const float*)d_in[7];
  const float* Ws0     = (const float*)d_in[8];
  const float* Wn0     = (const float*)d_in[9];
  const float* b0      = (const float*)d_in[10];
  const float* g0      = (const float*)d_in[11];
  const float* be0     = (const float*)d_in[12];
  const float* Ws1     = (const float*)d_in[13];
  const float* Wn1     = (const float*)d_in[14];
  const float* b1      = (const float*)d_in[15];
  const float* g1      = (const float*)d_in[16];
  const float* be1     = (const float*)d_in[17];
  const float* W1      = (const float*)d_in[18];
  const float* bm1     = (const float*)d_in[19];
  const float* W2      = (const float*)d_in[20];
  const float* bm2     = (const float*)d_in[21];
  float* out = (float*)d_out;

  float* ws = (float*)d_ws;
  // region map (float offsets); total ~18.0M floats = 72 MB
  __hip_bfloat16* xb    = (__hip_bfloat16*)(ws + 0);         // 200K*64 bf16 (dead after sage0)
  __hip_bfloat16* h2b   = (__hip_bfloat16*)(ws + 0);         // 50K*128 bf16 (written by sage1)
  __hip_bfloat16* meanb = (__hip_bfloat16*)(ws + 6400000);   // mean L0 (100K*64) / mean L1 (50K*128)
  __hip_bfloat16* h1b   = (__hip_bfloat16*)(ws + 9600000);   // 100K*128 bf16
  __hip_bfloat16* wT0   = (__hip_bfloat16*)(ws + 16000000);  // 16384 bf16
  __hip_bfloat16* wT1   = (__hip_bfloat16*)(ws + 16010000);  // 32768 bf16
  __hip_bfloat16* w1tb  = (__hip_bfloat16*)(ws + 16030000);  // 34816 bf16
  float* s0   = ws + 16050000;                               // 256
  float* s1   = ws + 16050256;                               // 256
  int*   offA = (int*)(ws + 16060000);                       // 100001
  int*   curA = (int*)(ws + 16170000);                       // 100000
  int*   cntA = (int*)(ws + 16280000);                       // 100000
  int*   bsum = (int*)(ws + 16390000);                       // 512
  int*   srcs = (int*)(ws + 16400000);                       // 1.6M

  // ---- prep ----
  hipMemsetAsync(s0, 0, 512 * sizeof(float), stream);        // covers s0+s1
  k_prep<<<(16384 + 32768 + 34816 + 255) / 256, 256, 0, stream>>>(
      Ws0, Wn0, Ws1, Wn1, W1, wT0, wT1, w1tb);
  k_f2b4<<<2048, 256, 0, stream>>>(x_nodes, xb, CN0 * CIN / 4);

  // ---- layer 0: sort edges by dst ----
  hipMemsetAsync(cntA, 0, CN1 * sizeof(int), stream);
  k_hist<<<(CE0 + 255) / 256, 256, 0, stream>>>(dst0, CE0, cntA);
  {
    int nblk = (CN1 + 1023) / 1024;
    k_scan1<<<nblk, 256, 0, stream>>>(cntA, CN1, offA, bsum);
    k_scan2<<<1, 256, 0, stream>>>(bsum, nblk);
    k_scan3<<<(CN1 + 256) / 256, 256, 0, stream>>>(offA, curA, bsum, CN1, CE0);
  }
  k_reorder<<<(CE0 + 255) / 256, 256, 0, stream>>>(src0, dst0, CE0, curA, srcs);

  // ---- layer 0: gather + sage(MFMA) + bn ----
  k_gather64b<<<(CN1 + 3) / 4, 256, 0, stream>>>(xb, offA, srcs, meanb, CN1);
  k_sage_mfma<CIN><<<(CN1 + 63) / 64, 256, 0, stream>>>(xb, meanb, wT0, b0, h1b, CN1);
  k_colstats_b<<<256, 256, 0, stream>>>(h1b, CN1, s0);
  k_bnrelu_b<<<2048, 256, 0, stream>>>(h1b, CN1, s0, g0, be0);

  // ---- layer 1: sort edges by dst ----
  hipMemsetAsync(cntA, 0, CN2 * sizeof(int), stream);
  k_hist<<<(CE1 + 255) / 256, 256, 0, stream>>>(dst1, CE1, cntA);
  {
    int nblk = (CN2 + 1023) / 1024;
    k_scan1<<<nblk, 256, 0, stream>>>(cntA, CN2, offA, bsum);
    k_scan2<<<1, 256, 0, stream>>>(bsum, nblk);
    k_scan3<<<(CN2 + 256) / 256, 256, 0, stream>>>(offA, curA, bsum, CN2, CE1);
  }
  k_reorder<<<(CE1 + 255) / 256, 256, 0, stream>>>(src1, dst1, CE1, curA, srcs);

  // ---- layer 1: gather + sage(MFMA) + bn ----
  k_gather128b<<<(CN2 + 3) / 4, 256, 0, stream>>>(h1b, offA, srcs, meanb, CN2);
  k_sage_mfma<CH><<<(CN2 + 63) / 64, 256, 0, stream>>>(h1b, meanb, wT1, b1, h2b, CN2);
  k_colstats_b<<<256, 256, 0, stream>>>(h2b, CN2, s1);
  k_bnrelu_b<<<2048, 256, 0, stream>>>(h2b, CN2, s1, g1, be1);

  // ---- edge MLP (MFMA) ----
  k_edge_mfma<<<(CEP + 63) / 64, 256, 0, stream>>>(h2b, u, v, e_feat, w1tb, bm1, W2, bm2, out);
}

// Round 6
// 781.734 us; speedup vs baseline: 2.7883x; 1.0234x over previous
//
#include <hip/hip_runtime.h>
#include <hip/hip_bf16.h>

#define CN0 200000
#define CN1 100000
#define CN2 50000
#define CE0 1600000
#define CE1 800000
#define CEP 500000
#define CIN 64
#define CH  128
#define CEIN 16
#define CMH 128
#define CNCLS 8

typedef __bf16 bf16x8 __attribute__((ext_vector_type(8)));
typedef float  f32x4  __attribute__((ext_vector_type(4)));
typedef unsigned short u16x8 __attribute__((ext_vector_type(8)));
typedef unsigned short u16x4 __attribute__((ext_vector_type(4)));

__device__ inline float b2f(unsigned short u) {
  union { unsigned int i; float f; } x; x.i = ((unsigned int)u) << 16; return x.f;
}
__device__ inline unsigned short f2bu(float f) {
  __hip_bfloat16 h = __float2bfloat16(f);
  return *reinterpret_cast<unsigned short*>(&h);
}

// ---------------- histogram: cnt[dst[e]]++ ----------------
__global__ void k_hist(const int* __restrict__ dst, int n, int* __restrict__ cnt) {
  int i = blockIdx.x * blockDim.x + threadIdx.x;
  if (i < n) atomicAdd(&cnt[dst[i]], 1);
}

// ---------------- scan phase 1 ----------------
__global__ __launch_bounds__(256) void k_scan1(const int* __restrict__ cnt, int n,
                                               int* __restrict__ excl, int* __restrict__ bsum) {
  __shared__ int sh[256];
  int t = threadIdx.x;
  int base = blockIdx.x * 1024 + t * 4;
  int v[4];
#pragma unroll
  for (int i = 0; i < 4; i++) v[i] = (base + i < n) ? cnt[base + i] : 0;
  int tsum = v[0] + v[1] + v[2] + v[3];
  sh[t] = tsum; __syncthreads();
  for (int ofs = 1; ofs < 256; ofs <<= 1) {
    int x = (t >= ofs) ? sh[t - ofs] : 0; __syncthreads();
    sh[t] += x; __syncthreads();
  }
  int run = sh[t] - tsum;
  if (t == 255) bsum[blockIdx.x] = sh[255];
#pragma unroll
  for (int i = 0; i < 4; i++) {
    if (base + i < n) excl[base + i] = run;
    run += v[i];
  }
}

// ---------------- scan phase 2 ----------------
__global__ __launch_bounds__(256) void k_scan2(int* __restrict__ bsum, int n) {
  __shared__ int sh[256];
  int t = threadIdx.x;
  int v = (t < n) ? bsum[t] : 0;
  sh[t] = v; __syncthreads();
  for (int ofs = 1; ofs < 256; ofs <<= 1) {
    int x = (t >= ofs) ? sh[t - ofs] : 0; __syncthreads();
    sh[t] += x; __syncthreads();
  }
  if (t < n) bsum[t] = sh[t] - v;
}

// ---------------- scan phase 3 ----------------
__global__ void k_scan3(int* __restrict__ off, int* __restrict__ cur,
                        const int* __restrict__ bsum, int n, int total) {
  int i = blockIdx.x * blockDim.x + threadIdx.x;
  if (i < n) {
    int vv = off[i] + bsum[i >> 10];
    off[i] = vv; cur[i] = vv;
  }
  if (i == n) off[n] = total;
}

// ---------------- reorder ----------------
__global__ void k_reorder(const int* __restrict__ src, const int* __restrict__ dst,
                          int n, int* __restrict__ cur, int* __restrict__ srcs) {
  int i = blockIdx.x * blockDim.x + threadIdx.x;
  if (i < n) {
    int p = atomicAdd(&cur[dst[i]], 1);
    srcs[p] = src[i];
  }
}

// ---------------- gather-mean 64-wide: 1 node/wave, 8 parallel edges ----------------
__global__ __launch_bounds__(256) void k_gather64b(
    const __hip_bfloat16* __restrict__ xb, const int* __restrict__ off,
    const int* __restrict__ srcs, __hip_bfloat16* __restrict__ meanb, int nnodes) {
  int node = blockIdx.x * 4 + (threadIdx.x >> 6);
  if (node >= nnodes) return;
  int lane = threadIdx.x & 63;
  int g = lane >> 3;            // 8 edge groups
  int f8 = (lane & 7) * 8;      // feature offset
  int s = off[node], e = off[node + 1];
  float acc[8] = {0.f,0.f,0.f,0.f,0.f,0.f,0.f,0.f};
  for (int p = s + g; p < e; p += 8) {
    int sn = srcs[p];
    u16x8 v = *reinterpret_cast<const u16x8*>(xb + (long long)sn * CIN + f8);
#pragma unroll
    for (int j = 0; j < 8; j++) acc[j] += b2f(v[j]);
  }
#pragma unroll
  for (int m = 8; m < 64; m <<= 1)
#pragma unroll
    for (int j = 0; j < 8; j++) acc[j] += __shfl_xor(acc[j], m, 64);
  if (g == 0) {
    float inv = 1.0f / (float)max(e - s, 1);
    u16x8 o;
#pragma unroll
    for (int j = 0; j < 8; j++) o[j] = f2bu(acc[j] * inv);
    *reinterpret_cast<u16x8*>(meanb + (long long)node * CIN + f8) = o;
  }
}

// ---------------- gather-mean 128-wide: 1 node/wave, 4 parallel edges ----------------
__global__ __launch_bounds__(256) void k_gather128b(
    const __hip_bfloat16* __restrict__ hb, const int* __restrict__ off,
    const int* __restrict__ srcs, __hip_bfloat16* __restrict__ meanb, int nnodes) {
  int node = blockIdx.x * 4 + (threadIdx.x >> 6);
  if (node >= nnodes) return;
  int lane = threadIdx.x & 63;
  int g = lane >> 4;            // 4 edge groups
  int f8 = (lane & 15) * 8;     // feature offset
  int s = off[node], e = off[node + 1];
  float acc[8] = {0.f,0.f,0.f,0.f,0.f,0.f,0.f,0.f};
  for (int p = s + g; p < e; p += 4) {
    int sn = srcs[p];
    u16x8 v = *reinterpret_cast<const u16x8*>(hb + (long long)sn * CH + f8);
#pragma unroll
    for (int j = 0; j < 8; j++) acc[j] += b2f(v[j]);
  }
#pragma unroll
  for (int m = 16; m < 64; m <<= 1)
#pragma unroll
    for (int j = 0; j < 8; j++) acc[j] += __shfl_xor(acc[j], m, 64);
  if (g == 0) {
    float inv = 1.0f / (float)max(e - s, 1);
    u16x8 o;
#pragma unroll
    for (int j = 0; j < 8; j++) o[j] = f2bu(acc[j] * inv);
    *reinterpret_cast<u16x8*>(meanb + (long long)node * CH + f8) = o;
  }
}

// ---------------- SAGE layer via MFMA + fused column stats ----------------
// outb = [A1|A2] @ wT^T + bias (bf16); stats[c] += col-sum, stats[128+c] += col-sumsq
template<int KA>
__global__ __launch_bounds__(256) void k_sage_mfma(
    const __hip_bfloat16* __restrict__ A1, const __hip_bfloat16* __restrict__ A2,
    const __hip_bfloat16* __restrict__ wT, const float* __restrict__ bias,
    __hip_bfloat16* __restrict__ outb, float* __restrict__ stats, int M) {
  __shared__ float ssum[CH], ssq[CH];
  int tid = threadIdx.x;
  int lane = tid & 63;
  int w = tid >> 6;
  int wm = w & 1, wn = w >> 1;
  int l15 = lane & 15, lk = lane >> 4;
  int r0 = blockIdx.x * 64;

  if (tid < CH) { ssum[tid] = 0.f; ssq[tid] = 0.f; }

  int rA = r0 + wm * 32 + l15;
  int rB = rA + 16;
  int rAc = min(rA, M - 1), rBc = min(rB, M - 1);
  const __hip_bfloat16* a1A = A1 + (long long)rAc * KA + lk * 8;
  const __hip_bfloat16* a1B = A1 + (long long)rBc * KA + lk * 8;
  const __hip_bfloat16* a2A = A2 + (long long)rAc * KA + lk * 8;
  const __hip_bfloat16* a2B = A2 + (long long)rBc * KA + lk * 8;
  const __hip_bfloat16* wp[4];
#pragma unroll
  for (int nf = 0; nf < 4; nf++)
    wp[nf] = wT + (long long)(wn * 64 + nf * 16 + l15) * (2 * KA) + lk * 8;

  f32x4 acc[2][4];
#pragma unroll
  for (int nf = 0; nf < 4; nf++) {
    float bv = bias[wn * 64 + nf * 16 + l15];
#pragma unroll
    for (int m = 0; m < 2; m++) {
      acc[m][nf][0] = bv; acc[m][nf][1] = bv;
      acc[m][nf][2] = bv; acc[m][nf][3] = bv;
    }
  }

  constexpr int HS = KA / 32;
#pragma unroll
  for (int kk = 0; kk < 2 * HS; kk++) {
    bf16x8 a0, a1v;
    if (kk < HS) {
      a0  = *reinterpret_cast<const bf16x8*>(a1A + kk * 32);
      a1v = *reinterpret_cast<const bf16x8*>(a1B + kk * 32);
    } else {
      a0  = *reinterpret_cast<const bf16x8*>(a2A + (kk - HS) * 32);
      a1v = *reinterpret_cast<const bf16x8*>(a2B + (kk - HS) * 32);
    }
#pragma unroll
    for (int nf = 0; nf < 4; nf++) {
      bf16x8 b = *reinterpret_cast<const bf16x8*>(wp[nf] + kk * 32);
      acc[0][nf] = __builtin_amdgcn_mfma_f32_16x16x32_bf16(a0,  b, acc[0][nf], 0, 0, 0);
      acc[1][nf] = __builtin_amdgcn_mfma_f32_16x16x32_bf16(a1v, b, acc[1][nf], 0, 0, 0);
    }
  }
  __syncthreads();   // ssum/ssq init visible

  unsigned short* ob = reinterpret_cast<unsigned short*>(outb);
#pragma unroll
  for (int nf = 0; nf < 4; nf++) {
    float cs = 0.f, cq = 0.f;
#pragma unroll
    for (int m = 0; m < 2; m++)
#pragma unroll
      for (int r = 0; r < 4; r++) {
        int row = r0 + wm * 32 + m * 16 + lk * 4 + r;
        if (row < M) {
          float v = acc[m][nf][r];
          cs += v; cq = fmaf(v, v, cq);
          ob[(long long)row * CH + wn * 64 + nf * 16 + l15] = f2bu(v);
        }
      }
    // reduce over lk groups (lane bits 4,5)
    cs += __shfl_xor(cs, 16, 64); cq += __shfl_xor(cq, 16, 64);
    cs += __shfl_xor(cs, 32, 64); cq += __shfl_xor(cq, 32, 64);
    if (lk == 0) {
      atomicAdd(&ssum[wn * 64 + nf * 16 + l15], cs);
      atomicAdd(&ssq [wn * 64 + nf * 16 + l15], cq);
    }
  }
  __syncthreads();
  if (tid < CH) {
    atomicAdd(&stats[tid], ssum[tid]);
    atomicAdd(&stats[CH + tid], ssq[tid]);
  }
}

// ---------------- BN + ReLU on bf16 h, in place ----------------
__global__ void k_bnrelu_b(__hip_bfloat16* __restrict__ h, int nrows,
                           const float* __restrict__ stats,
                           const float* __restrict__ g, const float* __restrict__ be) {
  int total8 = nrows * (CH / 8);
  float inv_n = 1.0f / (float)nrows;
  for (int i = blockIdx.x * blockDim.x + threadIdx.x; i < total8;
       i += gridDim.x * blockDim.x) {
    int cg = (i & 15) * 8;
    u16x8 v = reinterpret_cast<u16x8*>(h)[i];
    u16x8 o;
#pragma unroll
    for (int j = 0; j < 8; j++) {
      int c = cg + j;
      float mu = stats[c] * inv_n;
      float var = stats[CH + c] * inv_n - mu * mu;
      float rs = rsqrtf(var + 1e-5f);
      float val = (b2f(v[j]) - mu) * rs * g[c] + be[c];
      o[j] = f2bu(fmaxf(val, 0.0f));
    }
    reinterpret_cast<u16x8*>(h)[i] = o;
  }
}

// ---------------- x fp32 -> bf16, vectorized ----------------
__global__ void k_f2b4(const float* __restrict__ src, __hip_bfloat16* __restrict__ dst, int n4) {
  for (int i = blockIdx.x * blockDim.x + threadIdx.x; i < n4; i += gridDim.x * blockDim.x) {
    float4 v = reinterpret_cast<const float4*>(src)[i];
    u16x4 o; o[0] = f2bu(v.x); o[1] = f2bu(v.y); o[2] = f2bu(v.z); o[3] = f2bu(v.w);
    reinterpret_cast<u16x4*>(dst)[i] = o;
  }
}

// ---------------- weight prep: wT0[128][128], wT1[128][256], w1t[128][272], w2t[16][128] ----
__global__ void k_prep(const float* __restrict__ Ws0, const float* __restrict__ Wn0,
                       const float* __restrict__ Ws1, const float* __restrict__ Wn1,
                       const float* __restrict__ W1, const float* __restrict__ W2,
                       __hip_bfloat16* __restrict__ wT0, __hip_bfloat16* __restrict__ wT1,
                       __hip_bfloat16* __restrict__ w1t, __hip_bfloat16* __restrict__ w2t) {
  int t = blockIdx.x * blockDim.x + threadIdx.x;
  if (t < 16384) {
    int n = t >> 7, k = t & 127;
    wT0[t] = __float2bfloat16(k < 64 ? Ws0[k * CH + n] : Wn0[(k - 64) * CH + n]);
    return;
  }
  t -= 16384;
  if (t < 32768) {
    int n = t >> 8, k = t & 255;
    wT1[t] = __float2bfloat16(k < 128 ? Ws1[k * CH + n] : Wn1[(k - 128) * CH + n]);
    return;
  }
  t -= 32768;
  if (t < 34816) {
    int n = t / 272, k = t % 272;
    w1t[t] = __float2bfloat16(W1[k * CMH + n]);
    return;
  }
  t -= 34816;
  if (t < 2048) {
    int c = t >> 7, k = t & 127;
    w2t[t] = __float2bfloat16(c < CNCLS ? W2[k * CNCLS + c] : 0.0f);
  }
}

// ---------------- edge MLP via bf16 MFMA (both GEMMs) ----------------
__global__ __launch_bounds__(256) void k_edge_mfma(
    const __hip_bfloat16* __restrict__ h2b, const int* __restrict__ u,
    const int* __restrict__ v, const float* __restrict__ ef,
    const __hip_bfloat16* __restrict__ w1t, const float* __restrict__ bm1,
    const __hip_bfloat16* __restrict__ w2t, const float* __restrict__ bm2,
    float* __restrict__ out) {
  __shared__ __align__(16) unsigned short hid[64][152];   // bf16, 19.0 KB, 304B stride
  int tid = threadIdx.x;
  int lane = tid & 63;
  int w = tid >> 6;
  int wm = w & 1;
  int wn = w >> 1;
  int l15 = lane & 15, lk = lane >> 4;
  int e0 = blockIdx.x * 64;

  int eA = e0 + wm * 32 + l15;
  int eB = eA + 16;
  int eAc = min(eA, CEP - 1), eBc = min(eB, CEP - 1);
  int uA = u[eAc], uB = u[eBc], vA = v[eAc], vB = v[eBc];

  const __hip_bfloat16* auP = h2b + (long long)uA * CH + lk * 8;
  const __hip_bfloat16* buP = h2b + (long long)uB * CH + lk * 8;
  const __hip_bfloat16* avP = h2b + (long long)vA * CH + lk * 8;
  const __hip_bfloat16* bvP = h2b + (long long)vB * CH + lk * 8;

  const __hip_bfloat16* wb[4];
#pragma unroll
  for (int nf = 0; nf < 4; nf++)
    wb[nf] = w1t + (long long)(wn * 64 + nf * 16 + l15) * (2 * CH + CEIN) + lk * 8;

  // e_feat fragment (k=256..271), fp32 float4 loads -> bf16 in-reg; valid lanes lk<2
  bf16x8 zf = {};
  bf16x8 aefA = zf, aefB = zf;
  if (lk < 2) {
    const float* pA = ef + (long long)eAc * CEIN + lk * 8;
    const float* pB = ef + (long long)eBc * CEIN + lk * 8;
    float4 a0 = *reinterpret_cast<const float4*>(pA);
    float4 a1 = *reinterpret_cast<const float4*>(pA + 4);
    float4 b0 = *reinterpret_cast<const float4*>(pB);
    float4 b1 = *reinterpret_cast<const float4*>(pB + 4);
    u16x8 ua, ub;
    ua[0]=f2bu(a0.x); ua[1]=f2bu(a0.y); ua[2]=f2bu(a0.z); ua[3]=f2bu(a0.w);
    ua[4]=f2bu(a1.x); ua[5]=f2bu(a1.y); ua[6]=f2bu(a1.z); ua[7]=f2bu(a1.w);
    ub[0]=f2bu(b0.x); ub[1]=f2bu(b0.y); ub[2]=f2bu(b0.z); ub[3]=f2bu(b0.w);
    ub[4]=f2bu(b1.x); ub[5]=f2bu(b1.y); ub[6]=f2bu(b1.z); ub[7]=f2bu(b1.w);
    aefA = *reinterpret_cast<bf16x8*>(&ua);
    aefB = *reinterpret_cast<bf16x8*>(&ub);
  }

  f32x4 acc[2][4];
#pragma unroll
  for (int nf = 0; nf < 4; nf++) {
    float bias = bm1[wn * 64 + nf * 16 + l15];
#pragma unroll
    for (int m = 0; m < 2; m++) {
      acc[m][nf][0] = bias; acc[m][nf][1] = bias;
      acc[m][nf][2] = bias; acc[m][nf][3] = bias;
    }
  }

#pragma unroll
  for (int kk = 0; kk < 9; kk++) {
    bf16x8 a0, a1;
    if (kk < 4) {
      a0 = *reinterpret_cast<const bf16x8*>(auP + kk * 32);
      a1 = *reinterpret_cast<const bf16x8*>(buP + kk * 32);
    } else if (kk < 8) {
      a0 = *reinterpret_cast<const bf16x8*>(avP + (kk - 4) * 32);
      a1 = *reinterpret_cast<const bf16x8*>(bvP + (kk - 4) * 32);
    } else {
      a0 = aefA;
      a1 = aefB;
    }
#pragma unroll
    for (int nf = 0; nf < 4; nf++) {
      bf16x8 b;
      if (kk < 8) b = *reinterpret_cast<const bf16x8*>(wb[nf] + kk * 32);
      else        b = (lk < 2) ? *reinterpret_cast<const bf16x8*>(wb[nf] + 256) : zf;
      acc[0][nf] = __builtin_amdgcn_mfma_f32_16x16x32_bf16(a0, b, acc[0][nf], 0, 0, 0);
      acc[1][nf] = __builtin_amdgcn_mfma_f32_16x16x32_bf16(a1, b, acc[1][nf], 0, 0, 0);
    }
  }

#pragma unroll
  for (int m = 0; m < 2; m++)
#pragma unroll
    for (int nf = 0; nf < 4; nf++)
#pragma unroll
      for (int r = 0; r < 4; r++) {
        int row = wm * 32 + m * 16 + lk * 4 + r;
        int col = wn * 64 + nf * 16 + l15;
        hid[row][col] = f2bu(fmaxf(acc[m][nf][r], 0.0f));
      }
  __syncthreads();

  // GEMM2 via MFMA: each wave does 16 edges x 16 cols (8 valid) over K=128
  {
    int we = w * 16;
    const __hip_bfloat16* w2p = w2t + (long long)l15 * CMH + lk * 8;
    float bv2 = (l15 < CNCLS) ? bm2[l15] : 0.0f;
    f32x4 o; o[0] = bv2; o[1] = bv2; o[2] = bv2; o[3] = bv2;
#pragma unroll
    for (int kk = 0; kk < 4; kk++) {
      bf16x8 a = *reinterpret_cast<const bf16x8*>(
          reinterpret_cast<const unsigned short*>(&hid[we + l15][0]) + kk * 32 + lk * 8);
      bf16x8 b = *reinterpret_cast<const bf16x8*>(w2p + kk * 32);
      o = __builtin_amdgcn_mfma_f32_16x16x32_bf16(a, b, o, 0, 0, 0);
    }
    if (l15 < CNCLS) {
#pragma unroll
      for (int r = 0; r < 4; r++) {
        int e = e0 + we + lk * 4 + r;
        if (e < CEP) out[(long long)e * CNCLS + l15] = o[r];
      }
    }
  }
}

// ---------------- launch ----------------
extern "C" void kernel_launch(void* const* d_in, const int* in_sizes, int n_in,
                              void* d_out, int out_size, void* d_ws, size_t ws_size,
                              hipStream_t stream) {
  const float* x_nodes = (const float*)d_in[0];
  const int*   src0    = (const int*)d_in[1];
  const int*   dst0    = (const int*)d_in[2];
  const int*   src1    = (const int*)d_in[3];
  const int*   dst1    = (const int*)d_in[4];
  const int*   u       = (const int*)d_in[5];
  const int*   v       = (const int*)d_in[6];
  const float* e_feat  = (const float*)d_in[7];
  const float* Ws0     = (const float*)d_in[8];
  const float* Wn0     = (const float*)d_in[9];
  const float* b0      = (const float*)d_in[10];
  const float* g0      = (const float*)d_in[11];
  const float* be0     = (const float*)d_in[12];
  const float* Ws1     = (const float*)d_in[13];
  const float* Wn1     = (const float*)d_in[14];
  const float* b1      = (const float*)d_in[15];
  const float* g1      = (const float*)d_in[16];
  const float* be1     = (const float*)d_in[17];
  const float* W1      = (const float*)d_in[18];
  const float* bm1     = (const float*)d_in[19];
  const float* W2      = (const float*)d_in[20];
  const float* bm2     = (const float*)d_in[21];
  float* out = (float*)d_out;

  float* ws = (float*)d_ws;
  __hip_bfloat16* xb    = (__hip_bfloat16*)(ws + 0);         // 200K*64 bf16 (dead after sage0)
  __hip_bfloat16* h2b   = (__hip_bfloat16*)(ws + 0);         // 50K*128 bf16 (written by sage1)
  __hip_bfloat16* meanb = (__hip_bfloat16*)(ws + 6400000);   // mean L0 / mean L1
  __hip_bfloat16* h1b   = (__hip_bfloat16*)(ws + 9600000);   // 100K*128 bf16
  __hip_bfloat16* wT0   = (__hip_bfloat16*)(ws + 16000000);  // 16384 bf16
  __hip_bfloat16* wT1   = (__hip_bfloat16*)(ws + 16010000);  // 32768 bf16
  __hip_bfloat16* w1tb  = (__hip_bfloat16*)(ws + 16030000);  // 34816 bf16
  __hip_bfloat16* w2tb  = (__hip_bfloat16*)(ws + 16048000);  // 2048 bf16
  float* s0   = ws + 16050000;                               // 256
  float* s1   = ws + 16050256;                               // 256
  int*   offA = (int*)(ws + 16060000);                       // 100001
  int*   curA = (int*)(ws + 16170000);                       // 100000
  int*   cntA = (int*)(ws + 16280000);                       // 100000
  int*   bsum = (int*)(ws + 16390000);                       // 512
  int*   srcs = (int*)(ws + 16400000);                       // 1.6M

  // ---- prep ----
  hipMemsetAsync(s0, 0, 512 * sizeof(float), stream);        // covers s0+s1
  k_prep<<<(16384 + 32768 + 34816 + 2048 + 255) / 256, 256, 0, stream>>>(
      Ws0, Wn0, Ws1, Wn1, W1, W2, wT0, wT1, w1tb, w2tb);
  k_f2b4<<<2048, 256, 0, stream>>>(x_nodes, xb, CN0 * CIN / 4);

  // ---- layer 0: sort edges by dst ----
  hipMemsetAsync(cntA, 0, CN1 * sizeof(int), stream);
  k_hist<<<(CE0 + 255) / 256, 256, 0, stream>>>(dst0, CE0, cntA);
  {
    int nblk = (CN1 + 1023) / 1024;
    k_scan1<<<nblk, 256, 0, stream>>>(cntA, CN1, offA, bsum);
    k_scan2<<<1, 256, 0, stream>>>(bsum, nblk);
    k_scan3<<<(CN1 + 256) / 256, 256, 0, stream>>>(offA, curA, bsum, CN1, CE0);
  }
  k_reorder<<<(CE0 + 255) / 256, 256, 0, stream>>>(src0, dst0, CE0, curA, srcs);

  // ---- layer 0: gather + sage(MFMA, fused stats) + bn ----
  k_gather64b<<<(CN1 + 3) / 4, 256, 0, stream>>>(xb, offA, srcs, meanb, CN1);
  k_sage_mfma<CIN><<<(CN1 + 63) / 64, 256, 0, stream>>>(xb, meanb, wT0, b0, h1b, s0, CN1);
  k_bnrelu_b<<<2048, 256, 0, stream>>>(h1b, CN1, s0, g0, be0);

  // ---- layer 1: sort edges by dst ----
  hipMemsetAsync(cntA, 0, CN2 * sizeof(int), stream);
  k_hist<<<(CE1 + 255) / 256, 256, 0, stream>>>(dst1, CE1, cntA);
  {
    int nblk = (CN2 + 1023) / 1024;
    k_scan1<<<nblk, 256, 0, stream>>>(cntA, CN2, offA, bsum);
    k_scan2<<<1, 256, 0, stream>>>(bsum, nblk);
    k_scan3<<<(CN2 + 256) / 256, 256, 0, stream>>>(offA, curA, bsum, CN2, CE1);
  }
  k_reorder<<<(CE1 + 255) / 256, 256, 0, stream>>>(src1, dst1, CE1, curA, srcs);

  // ---- layer 1: gather + sage(MFMA, fused stats) + bn ----
  k_gather128b<<<(CN2 + 3) / 4, 256, 0, stream>>>(h1b, offA, srcs, meanb, CN2);
  k_sage_mfma<CH><<<(CN2 + 63) / 64, 256, 0, stream>>>(h1b, meanb, wT1, b1, h2b, s1, CN2);
  k_bnrelu_b<<<2048, 256, 0, stream>>>(h2b, CN2, s1, g1, be1);

  // ---- edge MLP (MFMA both GEMMs) ----
  k_edge_mfma<<<(CEP + 63) / 64, 256, 0, stream>>>(h2b, u, v, e_feat, w1tb, bm1, w2tb, bm2, out);
}

// Round 8
// 772.616 us; speedup vs baseline: 2.8212x; 1.0118x over previous
//
#include <hip/hip_runtime.h>
#include <hip/hip_bf16.h>

#define CN0 200000
#define CN1 100000
#define CN2 50000
#define CE0 1600000
#define CE1 800000
#define CEP 500000
#define CIN 64
#define CH  128
#define CEIN 16
#define CMH 128
#define CNCLS 8
#define NTOT (CN1 + CN2)      // 150000
#define ETOT (CE0 + CE1)      // 2400000

typedef __bf16 bf16x8 __attribute__((ext_vector_type(8)));
typedef float  f32x4  __attribute__((ext_vector_type(4)));
typedef unsigned short u16x8 __attribute__((ext_vector_type(8)));
typedef unsigned short u16x4 __attribute__((ext_vector_type(4)));

__device__ inline float b2f(unsigned short u) {
  union { unsigned int i; float f; } x; x.i = ((unsigned int)u) << 16; return x.f;
}
__device__ inline unsigned short f2bu(float f) {
  __hip_bfloat16 h = __float2bfloat16(f);
  return *reinterpret_cast<unsigned short*>(&h);
}

// ---------------- prep: weights->bf16 layouts + zero cnt/stats ----------------
// wT0[128][128] (sage0), wT1[128][256] (sage1), wab[256][128] (P-GEMM),
// w1cT[128][32] (ef part, k>=16 zero), w2t[16][128] (GEMM2, cols>=8 zero)
__global__ void k_prep(const float* __restrict__ Ws0, const float* __restrict__ Wn0,
                       const float* __restrict__ Ws1, const float* __restrict__ Wn1,
                       const float* __restrict__ W1, const float* __restrict__ W2,
                       __hip_bfloat16* __restrict__ wT0, __hip_bfloat16* __restrict__ wT1,
                       __hip_bfloat16* __restrict__ wab, __hip_bfloat16* __restrict__ w1cT,
                       __hip_bfloat16* __restrict__ w2t,
                       int* __restrict__ cnt, float* __restrict__ stats) {
  int t0 = blockIdx.x * blockDim.x + threadIdx.x;
  if (t0 < NTOT + 1) cnt[t0] = 0;
  if (t0 < 512) stats[t0] = 0.f;
  int t = t0;
  if (t < 16384) {
    int n = t >> 7, k = t & 127;
    wT0[t] = __float2bfloat16(k < 64 ? Ws0[k * CH + n] : Wn0[(k - 64) * CH + n]);
    return;
  }
  t -= 16384;
  if (t < 32768) {
    int n = t >> 8, k = t & 255;
    wT1[t] = __float2bfloat16(k < 128 ? Ws1[k * CH + n] : Wn1[(k - 128) * CH + n]);
    return;
  }
  t -= 32768;
  if (t < 32768) {
    int n = t >> 7, k = t & 127;
    wab[t] = __float2bfloat16(n < 128 ? W1[k * CMH + n] : W1[(128 + k) * CMH + (n - 128)]);
    return;
  }
  t -= 32768;
  if (t < 4096) {
    int n = t >> 5, k = t & 31;
    w1cT[t] = __float2bfloat16(k < CEIN ? W1[(256 + k) * CMH + n] : 0.0f);
    return;
  }
  t -= 4096;
  if (t < 2048) {
    int col = t >> 7, k = t & 127;
    w2t[t] = __float2bfloat16(col < CNCLS ? W2[k * CNCLS + col] : 0.0f);
  }
}

// ---------------- x fp32 -> bf16, vectorized ----------------
__global__ void k_f2b4(const float* __restrict__ src, __hip_bfloat16* __restrict__ dst, int n4) {
  for (int i = blockIdx.x * blockDim.x + threadIdx.x; i < n4; i += gridDim.x * blockDim.x) {
    float4 v = reinterpret_cast<const float4*>(src)[i];
    u16x4 o; o[0] = f2bu(v.x); o[1] = f2bu(v.y); o[2] = f2bu(v.z); o[3] = f2bu(v.w);
    reinterpret_cast<u16x4*>(dst)[i] = o;
  }
}

// ---------------- combined histogram over both layers ----------------
__global__ void k_hist2(const int* __restrict__ dst0, const int* __restrict__ dst1,
                        int* __restrict__ cnt) {
  int i = blockIdx.x * blockDim.x + threadIdx.x;
  if (i < CE0) atomicAdd(&cnt[dst0[i]], 1);
  else if (i < ETOT) atomicAdd(&cnt[CN1 + dst1[i - CE0]], 1);
}

// ---------------- scan phase 1: per-1024 exclusive scan ----------------
__global__ __launch_bounds__(256) void k_scan1(const int* __restrict__ cnt, int n,
                                               int* __restrict__ excl, int* __restrict__ bsum) {
  __shared__ int sh[256];
  int t = threadIdx.x;
  int base = blockIdx.x * 1024 + t * 4;
  int v[4];
#pragma unroll
  for (int i = 0; i < 4; i++) v[i] = (base + i < n) ? cnt[base + i] : 0;
  int tsum = v[0] + v[1] + v[2] + v[3];
  sh[t] = tsum; __syncthreads();
  for (int ofs = 1; ofs < 256; ofs <<= 1) {
    int x = (t >= ofs) ? sh[t - ofs] : 0; __syncthreads();
    sh[t] += x; __syncthreads();
  }
  int run = sh[t] - tsum;
  if (t == 255) bsum[blockIdx.x] = sh[255];
#pragma unroll
  for (int i = 0; i < 4; i++) {
    if (base + i < n) excl[base + i] = run;
    run += v[i];
  }
}

// ---------------- scan phase 2+3 fused: each block rescans bsum in LDS ----------------
__global__ __launch_bounds__(256) void k_scan23(int* __restrict__ off, int* __restrict__ cur,
                                                const int* __restrict__ bsum, int nblk,
                                                int n, int total) {
  __shared__ int sh[256];
  int t = threadIdx.x;
  int v = (t < nblk) ? bsum[t] : 0;
  sh[t] = v; __syncthreads();
  for (int ofs = 1; ofs < 256; ofs <<= 1) {
    int x = (t >= ofs) ? sh[t - ofs] : 0; __syncthreads();
    sh[t] += x; __syncthreads();
  }
  int i = blockIdx.x * 256 + t;
  if (i < n) {
    int grp = i >> 10;
    int add = grp ? sh[grp - 1] : 0;
    int vv = off[i] + add;
    off[i] = vv; cur[i] = vv;
  }
  if (i == n) off[n] = total;
}

// ---------------- combined reorder ----------------
__global__ void k_reorder2(const int* __restrict__ src0, const int* __restrict__ dst0,
                           const int* __restrict__ src1, const int* __restrict__ dst1,
                           int* __restrict__ cur, int* __restrict__ srcs) {
  int i = blockIdx.x * blockDim.x + threadIdx.x;
  if (i < CE0) {
    int p = atomicAdd(&cur[dst0[i]], 1);
    srcs[p] = src0[i];
  } else if (i < ETOT) {
    int p = atomicAdd(&cur[CN1 + dst1[i - CE0]], 1);
    srcs[p] = src1[i - CE0];
  }
}

// ---------------- gather-mean 64-wide: 1 node/wave, 8 parallel edges ----------------
__global__ __launch_bounds__(256) void k_gather64b(
    const __hip_bfloat16* __restrict__ xb, const int* __restrict__ off,
    const int* __restrict__ srcs, __hip_bfloat16* __restrict__ meanb, int nnodes) {
  int node = blockIdx.x * 4 + (threadIdx.x >> 6);
  if (node >= nnodes) return;
  int lane = threadIdx.x & 63;
  int g = lane >> 3;
  int f8 = (lane & 7) * 8;
  int s = off[node], e = off[node + 1];
  float acc[8] = {0.f,0.f,0.f,0.f,0.f,0.f,0.f,0.f};
  for (int p = s + g; p < e; p += 8) {
    int sn = srcs[p];
    u16x8 v = *reinterpret_cast<const u16x8*>(xb + (long long)sn * CIN + f8);
#pragma unroll
    for (int j = 0; j < 8; j++) acc[j] += b2f(v[j]);
  }
#pragma unroll
  for (int m = 8; m < 64; m <<= 1)
#pragma unroll
    for (int j = 0; j < 8; j++) acc[j] += __shfl_xor(acc[j], m, 64);
  if (g == 0) {
    float inv = 1.0f / (float)max(e - s, 1);
    u16x8 o;
#pragma unroll
    for (int j = 0; j < 8; j++) o[j] = f2bu(acc[j] * inv);
    *reinterpret_cast<u16x8*>(meanb + (long long)node * CIN + f8) = o;
  }
}

// ---------------- gather-mean 128-wide: 1 node/wave, 4 parallel edges ----------------
__global__ __launch_bounds__(256) void k_gather128b(
    const __hip_bfloat16* __restrict__ hb, const int* __restrict__ off,
    const int* __restrict__ srcs, __hip_bfloat16* __restrict__ meanb, int nnodes) {
  int node = blockIdx.x * 4 + (threadIdx.x >> 6);
  if (node >= nnodes) return;
  int lane = threadIdx.x & 63;
  int g = lane >> 4;
  int f8 = (lane & 15) * 8;
  int s = off[node], e = off[node + 1];
  float acc[8] = {0.f,0.f,0.f,0.f,0.f,0.f,0.f,0.f};
  for (int p = s + g; p < e; p += 4) {
    int sn = srcs[p];
    u16x8 v = *reinterpret_cast<const u16x8*>(hb + (long long)sn * CH + f8);
#pragma unroll
    for (int j = 0; j < 8; j++) acc[j] += b2f(v[j]);
  }
#pragma unroll
  for (int m = 16; m < 64; m <<= 1)
#pragma unroll
    for (int j = 0; j < 8; j++) acc[j] += __shfl_xor(acc[j], m, 64);
  if (g == 0) {
    float inv = 1.0f / (float)max(e - s, 1);
    u16x8 o;
#pragma unroll
    for (int j = 0; j < 8; j++) o[j] = f2bu(acc[j] * inv);
    *reinterpret_cast<u16x8*>(meanb + (long long)node * CH + f8) = o;
  }
}

// ---------------- SAGE layer via MFMA + fused column stats ----------------
template<int KA>
__global__ __launch_bounds__(256) void k_sage_mfma(
    const __hip_bfloat16* __restrict__ A1, const __hip_bfloat16* __restrict__ A2,
    const __hip_bfloat16* __restrict__ wT, const float* __restrict__ bias,
    __hip_bfloat16* __restrict__ outb, float* __restrict__ stats, int M) {
  __shared__ float ssum[CH], ssq[CH];
  int tid = threadIdx.x;
  int lane = tid & 63;
  int w = tid >> 6;
  int wm = w & 1, wn = w >> 1;
  int l15 = lane & 15, lk = lane >> 4;
  int r0 = blockIdx.x * 64;

  if (tid < CH) { ssum[tid] = 0.f; ssq[tid] = 0.f; }

  int rA = r0 + wm * 32 + l15;
  int rB = rA + 16;
  int rAc = min(rA, M - 1), rBc = min(rB, M - 1);
  const __hip_bfloat16* a1A = A1 + (long long)rAc * KA + lk * 8;
  const __hip_bfloat16* a1B = A1 + (long long)rBc * KA + lk * 8;
  const __hip_bfloat16* a2A = A2 + (long long)rAc * KA + lk * 8;
  const __hip_bfloat16* a2B = A2 + (long long)rBc * KA + lk * 8;
  const __hip_bfloat16* wp[4];
#pragma unroll
  for (int nf = 0; nf < 4; nf++)
    wp[nf] = wT + (long long)(wn * 64 + nf * 16 + l15) * (2 * KA) + lk * 8;

  f32x4 acc[2][4];
#pragma unroll
  for (int nf = 0; nf < 4; nf++) {
    float bv = bias[wn * 64 + nf * 16 + l15];
#pragma unroll
    for (int m = 0; m < 2; m++) {
      acc[m][nf][0] = bv; acc[m][nf][1] = bv;
      acc[m][nf][2] = bv; acc[m][nf][3] = bv;
    }
  }

  constexpr int HS = KA / 32;
#pragma unroll
  for (int kk = 0; kk < 2 * HS; kk++) {
    bf16x8 a0, a1v;
    if (kk < HS) {
      a0  = *reinterpret_cast<const bf16x8*>(a1A + kk * 32);
      a1v = *reinterpret_cast<const bf16x8*>(a1B + kk * 32);
    } else {
      a0  = *reinterpret_cast<const bf16x8*>(a2A + (kk - HS) * 32);
      a1v = *reinterpret_cast<const bf16x8*>(a2B + (kk - HS) * 32);
    }
#pragma unroll
    for (int nf = 0; nf < 4; nf++) {
      bf16x8 b = *reinterpret_cast<const bf16x8*>(wp[nf] + kk * 32);
      acc[0][nf] = __builtin_amdgcn_mfma_f32_16x16x32_bf16(a0,  b, acc[0][nf], 0, 0, 0);
      acc[1][nf] = __builtin_amdgcn_mfma_f32_16x16x32_bf16(a1v, b, acc[1][nf], 0, 0, 0);
    }
  }
  __syncthreads();

  unsigned short* ob = reinterpret_cast<unsigned short*>(outb);
#pragma unroll
  for (int nf = 0; nf < 4; nf++) {
    float cs = 0.f, cq = 0.f;
#pragma unroll
    for (int m = 0; m < 2; m++)
#pragma unroll
      for (int r = 0; r < 4; r++) {
        int row = r0 + wm * 32 + m * 16 + lk * 4 + r;
        if (row < M) {
          float v = acc[m][nf][r];
          cs += v; cq = fmaf(v, v, cq);
          ob[(long long)row * CH + wn * 64 + nf * 16 + l15] = f2bu(v);
        }
      }
    cs += __shfl_xor(cs, 16, 64); cq += __shfl_xor(cq, 16, 64);
    cs += __shfl_xor(cs, 32, 64); cq += __shfl_xor(cq, 32, 64);
    if (lk == 0) {
      atomicAdd(&ssum[wn * 64 + nf * 16 + l15], cs);
      atomicAdd(&ssq [wn * 64 + nf * 16 + l15], cq);
    }
  }
  __syncthreads();
  if (tid < CH) {
    atomicAdd(&stats[tid], ssum[tid]);
    atomicAdd(&stats[CH + tid], ssq[tid]);
  }
}

// ---------------- BN + ReLU on bf16 h, in place ----------------
__global__ void k_bnrelu_b(__hip_bfloat16* __restrict__ h, int nrows,
                           const float* __restrict__ stats,
                           const float* __restrict__ g, const float* __restrict__ be) {
  int total8 = nrows * (CH / 8);
  float inv_n = 1.0f / (float)nrows;
  for (int i = blockIdx.x * blockDim.x + threadIdx.x; i < total8;
       i += gridDim.x * blockDim.x) {
    int cg = (i & 15) * 8;
    u16x8 v = reinterpret_cast<u16x8*>(h)[i];
    u16x8 o;
#pragma unroll
    for (int j = 0; j < 8; j++) {
      int c = cg + j;
      float mu = stats[c] * inv_n;
      float var = stats[CH + c] * inv_n - mu * mu;
      float rs = rsqrtf(var + 1e-5f);
      float val = (b2f(v[j]) - mu) * rs * g[c] + be[c];
      o[j] = f2bu(fmaxf(val, 0.0f));
    }
    reinterpret_cast<u16x8*>(h)[i] = o;
  }
}

// ---------------- P-GEMM: paP[M][256] = h2b @ wab^T (bf16) ----------------
__global__ __launch_bounds__(256) void k_pgemm(
    const __hip_bfloat16* __restrict__ h2b, const __hip_bfloat16* __restrict__ wab,
    __hip_bfloat16* __restrict__ paP, int M) {
  int tid = threadIdx.x, lane = tid & 63, w = tid >> 6;
  int wm = w & 1, wn = w >> 1;
  int l15 = lane & 15, lk = lane >> 4;
  int r0 = blockIdx.x * 64;
  int rA = r0 + wm * 32 + l15, rB = rA + 16;
  int rAc = min(rA, M - 1), rBc = min(rB, M - 1);
  const __hip_bfloat16* aA = h2b + (long long)rAc * CH + lk * 8;
  const __hip_bfloat16* aB = h2b + (long long)rBc * CH + lk * 8;
  const __hip_bfloat16* wp[8];
#pragma unroll
  for (int nf = 0; nf < 8; nf++)
    wp[nf] = wab + (long long)(wn * 128 + nf * 16 + l15) * CH + lk * 8;

  f32x4 acc[2][8];
#pragma unroll
  for (int m = 0; m < 2; m++)
#pragma unroll
    for (int nf = 0; nf < 8; nf++) {
      acc[m][nf][0] = 0.f; acc[m][nf][1] = 0.f; acc[m][nf][2] = 0.f; acc[m][nf][3] = 0.f;
    }

#pragma unroll
  for (int kk = 0; kk < 4; kk++) {
    bf16x8 a0 = *reinterpret_cast<const bf16x8*>(aA + kk * 32);
    bf16x8 a1 = *reinterpret_cast<const bf16x8*>(aB + kk * 32);
#pragma unroll
    for (int nf = 0; nf < 8; nf++) {
      bf16x8 b = *reinterpret_cast<const bf16x8*>(wp[nf] + kk * 32);
      acc[0][nf] = __builtin_amdgcn_mfma_f32_16x16x32_bf16(a0, b, acc[0][nf], 0, 0, 0);
      acc[1][nf] = __builtin_amdgcn_mfma_f32_16x16x32_bf16(a1, b, acc[1][nf], 0, 0, 0);
    }
  }

  unsigned short* ob = reinterpret_cast<unsigned short*>(paP);
#pragma unroll
  for (int m = 0; m < 2; m++)
#pragma unroll
    for (int nf = 0; nf < 8; nf++)
#pragma unroll
      for (int r = 0; r < 4; r++) {
        int row = r0 + wm * 32 + m * 16 + lk * 4 + r;
        if (row < M)
          ob[(long long)row * 256 + wn * 128 + nf * 16 + l15] = f2bu(acc[m][nf][r]);
      }
}

// ---------------- edge kernel v3: hid = relu(Pa[u]+Pb[v]+ef@W1c+bm1); out = hid@W2+bm2 ----
__global__ __launch_bounds__(256) void k_edge_v3(
    const __hip_bfloat16* __restrict__ paP, const int* __restrict__ u,
    const int* __restrict__ v, const float* __restrict__ ef,
    const __hip_bfloat16* __restrict__ w1cT, const float* __restrict__ bm1,
    const __hip_bfloat16* __restrict__ w2t, const float* __restrict__ bm2,
    float* __restrict__ out) {
  __shared__ __align__(16) unsigned short hid[64][152];   // 19.0 KB
  int tid = threadIdx.x, lane = tid & 63, w = tid >> 6;
  int l15 = lane & 15, lk = lane >> 4;
  int e0 = blockIdx.x * 64;

  // ---- phase 1: hid = ef @ W1c + bm1 (16 edges per wave, K=32 padded) ----
  {
    int ec = min(e0 + w * 16 + l15, CEP - 1);
    bf16x8 a = {};
    if (lk < 2) {
      const float* p = ef + (long long)ec * CEIN + lk * 8;
      float4 x0 = *reinterpret_cast<const float4*>(p);
      float4 x1 = *reinterpret_cast<const float4*>(p + 4);
      u16x8 t;
      t[0]=f2bu(x0.x); t[1]=f2bu(x0.y); t[2]=f2bu(x0.z); t[3]=f2bu(x0.w);
      t[4]=f2bu(x1.x); t[5]=f2bu(x1.y); t[6]=f2bu(x1.z); t[7]=f2bu(x1.w);
      a = *reinterpret_cast<bf16x8*>(&t);
    }
#pragma unroll
    for (int nf = 0; nf < 8; nf++) {
      f32x4 acc;
      float bv = bm1[nf * 16 + l15];
      acc[0] = bv; acc[1] = bv; acc[2] = bv; acc[3] = bv;
      bf16x8 b = *reinterpret_cast<const bf16x8*>(w1cT + (nf * 16 + l15) * 32 + lk * 8);
      acc = __builtin_amdgcn_mfma_f32_16x16x32_bf16(a, b, acc, 0, 0, 0);
#pragma unroll
      for (int r = 0; r < 4; r++)
        hid[w * 16 + lk * 4 + r][nf * 16 + l15] = f2bu(acc[r]);
    }
  }
  __syncthreads();

  // ---- phase 2: hid = relu(hid + Pa[u] + Pb[v]) ----
  {
    int e = tid >> 2, q = tid & 3;
    int ec = min(e0 + e, CEP - 1);
    int ue = u[ec], ve = v[ec];
    const unsigned short* pa = reinterpret_cast<const unsigned short*>(paP)
                               + (long long)ue * 256 + q * 32;
    const unsigned short* pb = reinterpret_cast<const unsigned short*>(paP)
                               + (long long)ve * 256 + 128 + q * 32;
    u16x8 ra[4], rb[4], rh[4];
#pragma unroll
    for (int i = 0; i < 4; i++) {
      ra[i] = *reinterpret_cast<const u16x8*>(pa + i * 8);
      rb[i] = *reinterpret_cast<const u16x8*>(pb + i * 8);
      rh[i] = *reinterpret_cast<const u16x8*>(&hid[e][q * 32 + i * 8]);
    }
#pragma unroll
    for (int i = 0; i < 4; i++) {
      u16x8 o;
#pragma unroll
      for (int j = 0; j < 8; j++)
        o[j] = f2bu(fmaxf(b2f(rh[i][j]) + b2f(ra[i][j]) + b2f(rb[i][j]), 0.0f));
      *reinterpret_cast<u16x8*>(&hid[e][q * 32 + i * 8]) = o;
    }
  }
  __syncthreads();

  // ---- phase 3: GEMM2 via MFMA (16 edges x 16 cols per wave, K=128) ----
  {
    int we = w * 16;
    const __hip_bfloat16* w2p = w2t + (long long)l15 * CMH + lk * 8;
    float bv2 = (l15 < CNCLS) ? bm2[l15] : 0.0f;
    f32x4 o; o[0] = bv2; o[1] = bv2; o[2] = bv2; o[3] = bv2;
#pragma unroll
    for (int kk = 0; kk < 4; kk++) {
      bf16x8 a = *reinterpret_cast<const bf16x8*>(
          reinterpret_cast<const unsigned short*>(&hid[we + l15][0]) + kk * 32 + lk * 8);
      bf16x8 b = *reinterpret_cast<const bf16x8*>(w2p + kk * 32);
      o = __builtin_amdgcn_mfma_f32_16x16x32_bf16(a, b, o, 0, 0, 0);
    }
    if (l15 < CNCLS) {
#pragma unroll
      for (int r = 0; r < 4; r++) {
        int e = e0 + we + lk * 4 + r;
        if (e < CEP) out[(long long)e * CNCLS + l15] = o[r];
      }
    }
  }
}

// ---------------- launch ----------------
extern "C" void kernel_launch(void* const* d_in, const int* in_sizes, int n_in,
                              void* d_out, int out_size, void* d_ws, size_t ws_size,
                              hipStream_t stream) {
  const float* x_nodes = (const float*)d_in[0];
  const int*   src0    = (const int*)d_in[1];
  const int*   dst0    = (const int*)d_in[2];
  const int*   src1    = (const int*)d_in[3];
  const int*   dst1    = (const int*)d_in[4];
  const int*   u       = (const int*)d_in[5];
  const int*   v       = (const int*)d_in[6];
  const float* e_feat  = (const float*)d_in[7];
  const float* Ws0     = (const float*)d_in[8];
  const float* Wn0     = (const float*)d_in[9];
  const float* b0      = (const float*)d_in[10];
  const float* g0      = (const float*)d_in[11];
  const float* be0     = (const float*)d_in[12];
  const float* Ws1     = (const float*)d_in[13];
  const float* Wn1     = (const float*)d_in[14];
  const float* b1      = (const float*)d_in[15];
  const float* g1      = (const float*)d_in[16];
  const float* be1     = (const float*)d_in[17];
  const float* W1      = (const float*)d_in[18];
  const float* bm1     = (const float*)d_in[19];
  const float* W2      = (const float*)d_in[20];
  const float* bm2     = (const float*)d_in[21];
  float* out = (float*)d_out;

  float* ws = (float*)d_ws;
  // float-slot layout (no overlaps between concurrently-live buffers):
  // [0,      6.4M)  xb (200K*64 bf16)  -> reused as h2b (50K*128 bf16, [0,3.2M)) after sage0 consumed xb
  // [6.4M,   9.6M)  meanb (max 6.4M bf16)
  // [9.6M,  16.0M)  h1b (100K*128 bf16)
  // [16.0M, 22.4M)  paP (50K*256 bf16)
  __hip_bfloat16* xb    = (__hip_bfloat16*)(ws + 0);
  __hip_bfloat16* h2b   = (__hip_bfloat16*)(ws + 0);
  __hip_bfloat16* meanb = (__hip_bfloat16*)(ws + 6400000);
  __hip_bfloat16* h1b   = (__hip_bfloat16*)(ws + 9600000);
  __hip_bfloat16* paP   = (__hip_bfloat16*)(ws + 16000000);
  __hip_bfloat16* wT0   = (__hip_bfloat16*)(ws + 22400000);   // 16384 bf16
  __hip_bfloat16* wT1   = (__hip_bfloat16*)(ws + 22410000);   // 32768 bf16
  __hip_bfloat16* wab   = (__hip_bfloat16*)(ws + 22430000);   // 32768 bf16
  __hip_bfloat16* w1cT  = (__hip_bfloat16*)(ws + 22450000);   // 4096 bf16
  __hip_bfloat16* w2t   = (__hip_bfloat16*)(ws + 22453000);   // 2048 bf16
  float* stats = ws + 22455000;                               // 512 (s0,s1)
  float* s0 = stats;
  float* s1 = stats + 256;
  int*   off  = (int*)(ws + 22456000);                        // 150001
  int*   cur  = (int*)(ws + 22610000);                        // 150000
  int*   cnt  = (int*)(ws + 22770000);                        // 150001
  int*   bsum = (int*)(ws + 22930000);                        // 256
  int*   srcs = (int*)(ws + 22931000);                        // 2.4M ints -> ends 25.33M floats (~101 MB)

  // ---- prep (weights + zeroing) ----
  k_prep<<<(NTOT + 256) / 256, 256, 0, stream>>>(
      Ws0, Wn0, Ws1, Wn1, W1, W2, wT0, wT1, wab, w1cT, w2t, cnt, stats);
  k_f2b4<<<2048, 256, 0, stream>>>(x_nodes, xb, CN0 * CIN / 4);

  // ---- combined CSR build (both layers) ----
  k_hist2<<<(ETOT + 255) / 256, 256, 0, stream>>>(dst0, dst1, cnt);
  {
    int nblk = (NTOT + 1023) / 1024;   // 147
    k_scan1<<<nblk, 256, 0, stream>>>(cnt, NTOT, off, bsum);
    k_scan23<<<(NTOT + 256) / 256, 256, 0, stream>>>(off, cur, bsum, nblk, NTOT, ETOT);
  }
  k_reorder2<<<(ETOT + 255) / 256, 256, 0, stream>>>(src0, dst0, src1, dst1, cur, srcs);

  // ---- layer 0 ----
  k_gather64b<<<(CN1 + 3) / 4, 256, 0, stream>>>(xb, off, srcs, meanb, CN1);
  k_sage_mfma<CIN><<<(CN1 + 63) / 64, 256, 0, stream>>>(xb, meanb, wT0, b0, h1b, s0, CN1);
  k_bnrelu_b<<<2048, 256, 0, stream>>>(h1b, CN1, s0, g0, be0);

  // ---- layer 1 ----
  k_gather128b<<<(CN2 + 3) / 4, 256, 0, stream>>>(h1b, off + CN1, srcs, meanb, CN2);
  k_sage_mfma<CH><<<(CN2 + 63) / 64, 256, 0, stream>>>(h1b, meanb, wT1, b1, h2b, s1, CN2);
  k_bnrelu_b<<<1024, 256, 0, stream>>>(h2b, CN2, s1, g1, be1);

  // ---- per-node edge-MLP partials, then edge kernel ----
  k_pgemm<<<(CN2 + 63) / 64, 256, 0, stream>>>(h2b, wab, paP, CN2);
  k_edge_v3<<<(CEP + 63) / 64, 256, 0, stream>>>(paP, u, v, e_feat, w1cT, bm1, w2t, bm2, out);
}